// Round 11
// baseline (108.647 us; speedup 1.0000x reference)
//
#include <hip/hip_runtime.h>
#include <hip/hip_bf16.h>

// ---- problem constants ----
#define BB 8
#define TT 4096
#define DD 512
#define MM (BB*TT)          // 32768 rows
#define DECAYF 0.95f
#define OMDECAYF (1.0f - 0.95f)

typedef __attribute__((ext_vector_type(8))) short bf16x8;
typedef __attribute__((ext_vector_type(4))) float f32x4;

__device__ __forceinline__ float gelu_f(float x){
  return 0.5f * x * (1.0f + erff(x * 0.70710678118654752f));
}

__device__ __forceinline__ unsigned short f2bf(float x){
  unsigned u = __float_as_uint(x);
  unsigned r = (u + 0x7FFFu + ((u >> 16) & 1u)) >> 16;
  return (unsigned short)r;
}

// ====== K1: blocks 0-63  {spk_ctx coalesced GEMV + s_vec/coarse chunk}
//            blocks 64-127 transpose | blocks 128-135 scan+compaction ========
__global__ __launch_bounds__(512) void pre_kernel(
    const float* __restrict__ spk_embed, const float* __restrict__ spk_W,
    const float* __restrict__ spk_b, const float* __restrict__ rW1,
    const float* __restrict__ cW1, const float* __restrict__ cb1,
    const float* __restrict__ cW2, const float* __restrict__ grate,
    const float* __restrict__ la_g, const int* __restrict__ um,
    const int* __restrict__ sm, const int* __restrict__ zm,
    const float* __restrict__ stab_g, const float* __restrict__ lre,
    unsigned short* __restrict__ wqt, float* __restrict__ s_vec,
    float* __restrict__ coarse_part,
    float* __restrict__ rate_seq, float* __restrict__ rgate_a,
    int* __restrict__ active_list, int* __restrict__ acount)
{
  __shared__ float se[DD];
  __shared__ float scf[DD];
  __shared__ float red1[8][64];
  __shared__ float red2[8][64];
  __shared__ float tile[64][65];
  __shared__ float wAg[8], wBg[8], wSg[8];
  __shared__ int wcnt[8];
  int blk = blockIdx.x, t = threadIdx.x;
  int lane = t & 63, wid = t >> 6;

  if (blk < 64){
    // ---- phase A: full spk_ctx[b] via thread-per-column, COALESCED reads ----
    int b = blk >> 3, d0 = (blk & 7) * 64;
    se[t] = spk_embed[b*DD + t];
    __syncthreads();
    {
      float a = spk_b[t];
      const float* wp = spk_W + t;
      #pragma unroll 8
      for (int k = 0; k < DD; ++k) a = fmaf(se[k], wp[(long)k*DD], a);
      scf[t] = tanhf(a);
    }
    __syncthreads();
    // ---- phase B: s_vec chunk + coarse hidden partial (k-sliced waves) ----
    int dl = lane, ks = wid;
    float a1 = 0.f, a2 = 0.f;
    const float* wsp = rW1 + (long)(DD + ks*64)*DD + d0 + dl;   // Ws = res_W1[D:2D]
    const float* wcp = cW1 + (long)(ks*64)*DD + d0 + dl;
    #pragma unroll 4
    for (int k = 0; k < 64; ++k){
      float s = scf[ks*64 + k];
      a1 += s * wsp[(long)k*DD];
      a2 += s * wcp[(long)k*DD];
    }
    red1[ks][dl] = a1; red2[ks][dl] = a2;
    __syncthreads();
    if (t < 64){
      int d = d0 + t;
      float s1 = 0.f;
      float s2 = cb1[d] + grate[b] * cW1[(long)DD*DD + d];   // row 512 = grc coeff
      #pragma unroll
      for (int i = 0; i < 8; ++i){ s1 += red1[i][t]; s2 += red2[i][t]; }
      s_vec[b*DD + d] = s1;
      float hv = gelu_f(s2) * cW2[d];
      #pragma unroll
      for (int sh = 1; sh < 64; sh <<= 1) hv += __shfl_xor(hv, sh, 64);
      if (t == 0) coarse_part[blk] = hv;
    }
    return;
  }
  if (blk < 128){
    // ---- transpose Wq (k-major f32) -> WqT (n-major bf16) ----
    int tb = blk - 64;
    int nb = (tb & 7) * 64, kb = (tb >> 3) * 64;
    int tx = t & 63, ty = t >> 6;
    #pragma unroll
    for (int i = 0; i < 8; ++i){
      int k = ty + i*8;
      tile[k][tx] = rW1[(long)(kb + k)*DD + nb + tx];
    }
    __syncthreads();
    #pragma unroll
    for (int i = 0; i < 8; ++i){
      int nl = ty + i*8;
      wqt[(long)(nb + nl)*DD + kb + tx] = f2bf(tile[tx][nl]);
    }
    return;
  }

  // ---- scan: rate_seq + rgate + segmented compaction (batch b) ----
  int b = blk - 128;
  int base = b*TT + t*8;
  float4 la0 = *(const float4*)(la_g + base);
  float4 la1 = *(const float4*)(la_g + base + 4);
  int4 u0 = *(const int4*)(um + base), u1 = *(const int4*)(um + base + 4);
  int4 s0 = *(const int4*)(sm + base), s1 = *(const int4*)(sm + base + 4);
  int4 z0 = *(const int4*)(zm + base), z1 = *(const int4*)(zm + base + 4);
  float4 st0 = *(const float4*)(stab_g + base), st1 = *(const float4*)(stab_g + base + 4);
  float lav[8] = {la0.x,la0.y,la0.z,la0.w,la1.x,la1.y,la1.z,la1.w};
  int uv[8] = {u0.x,u0.y,u0.z,u0.w,u1.x,u1.y,u1.z,u1.w};
  int sv[8] = {s0.x,s0.y,s0.z,s0.w,s1.x,s1.y,s1.z,s1.w};
  int zv[8] = {z0.x,z0.y,z0.z,z0.w,z1.x,z1.y,z1.z,z1.w};
  float stv_[8] = {st0.x,st0.y,st0.z,st0.w,st1.x,st1.y,st1.z,st1.w};
  float spv[8], stv[8];

  float A = 1.f, Bv = 0.f, S = 0.f;
  #pragma unroll
  for (int i = 0; i < 8; ++i){
    float m = uv[i] > 0 ? 1.f : 0.f;
    float sealed = sv[i] > 0 ? 1.f : 0.f;
    float sil = (zv[i] > 0 ? 1.f : 0.f) * m;
    float speech = (m * sealed) * (1.f - sil);
    spv[i] = speech;
    stv[i] = fminf(fmaxf(stv_[i], 0.f), 1.f) * m;
    if (speech > 0.f){
      Bv = DECAYF*Bv + OMDECAYF*lav[i];
      A *= DECAYF;
      S += 1.f;
    }
  }
  #pragma unroll
  for (int d = 1; d < 64; d <<= 1){
    float Au = __shfl_up(A, d, 64);
    float Bu = __shfl_up(Bv, d, 64);
    float Su = __shfl_up(S, d, 64);
    if (lane >= d){ Bv = A*Bu + Bv; A = A*Au; S += Su; }
  }
  if (lane == 63){ wAg[wid] = A; wBg[wid] = Bv; wSg[wid] = S; }
  float Ale = __shfl_up(A, 1, 64), Ble = __shfl_up(Bv, 1, 64), Sle = __shfl_up(S, 1, 64);
  if (lane == 0){ Ale = 1.f; Ble = 0.f; Sle = 0.f; }
  __syncthreads();
  float Awp = 1.f, Bwp = 0.f, Swp = 0.f;
  for (int w = 0; w < wid; ++w){
    Bwp = wAg[w]*Bwp + wBg[w];
    Awp = wAg[w]*Awp;
    Swp += wSg[w];
  }
  float Bex = Ale*Bwp + Ble;
  float Aex = Ale*Awp;
  float Sex = Swp + Sle;

  float rate = Aex*lre[b] + Bex;
  float ps = Sex;
  float ro[8], rg[8];
  #pragma unroll
  for (int i = 0; i < 8; ++i){
    ro[i] = rate;
    float cold = fminf(ps * 0.5f, 1.f);                        // COLD_RUNS=2
    float shortg = fminf(fmaxf(expf(lav[i]) - 1.f, 0.f), 1.f); // MIN_DUR=2
    rg[i] = cold * shortg * stv[i] * spv[i];
    if (spv[i] > 0.f){
      rate = DECAYF*rate + OMDECAYF*lav[i];
      ps += 1.f;
    }
  }
  *(float4*)(rate_seq + base)     = make_float4(ro[0],ro[1],ro[2],ro[3]);
  *(float4*)(rate_seq + base + 4) = make_float4(ro[4],ro[5],ro[6],ro[7]);
  *(float4*)(rgate_a + base)      = make_float4(rg[0],rg[1],rg[2],rg[3]);
  *(float4*)(rgate_a + base + 4)  = make_float4(rg[4],rg[5],rg[6],rg[7]);

  int nact = 0;
  #pragma unroll
  for (int i = 0; i < 8; ++i) nact += (rg[i] != 0.f) ? 1 : 0;
  int inc = nact;
  #pragma unroll
  for (int d = 1; d < 64; d <<= 1){
    int u = __shfl_up(inc, d, 64);
    if (lane >= d) inc += u;
  }
  int myex = inc - nact;
  if (lane == 63) wcnt[wid] = inc;
  __syncthreads();
  int wbase = 0;
  for (int w = 0; w < wid; ++w) wbase += wcnt[w];
  int pos = wbase + myex;
  int* alist = active_list + b*TT;
  #pragma unroll
  for (int i = 0; i < 8; ++i){
    if (rg[i] != 0.f) alist[pos++] = base + i;
  }
  if (t == 0){
    int total = 0;
    #pragma unroll
    for (int w = 0; w < 8; ++w) total += wcnt[w];
    acount[b] = total;
  }
}

// ====== K2: persistent 256 blocks: baseline slice, then BM=64 gemm tiles =====
// BM=64, BN=512, BK=32, 8 waves; 2-buffer B staging, NO per-step barriers:
// wave wid stages AND reads only B-rows [64*wid, 64*wid+64) -> per-wave
// counted vmcnt is the only sync the K-loop needs (Af: one barrier after build).
// __launch_bounds__(512, 2): 2 waves/SIMD -> 256-VGPR budget -> acc[4][4]
// stays in registers (R10's plain (512) capped at 128 VGPR -> 90 MB spill).
__global__ __launch_bounds__(512, 2) void main_kernel(
    const int* __restrict__ content, const float* __restrict__ la_g,
    const float* __restrict__ sep, const float* __restrict__ edge,
    const float* __restrict__ emb, const float* __restrict__ fW,
    const float* __restrict__ fb, const float* __restrict__ rate_seq,
    const unsigned short* __restrict__ wqt,
    const float* __restrict__ s_vec, const float* __restrict__ rW1,
    const float* __restrict__ rb1, const float* __restrict__ rW2,
    const float* __restrict__ rb2, const float* __restrict__ grate,
    const float* __restrict__ coarse_part, const float* __restrict__ cb2,
    const int* __restrict__ um, const int* __restrict__ sm,
    const int* __restrict__ zm,
    const float* __restrict__ rgate_a, const int* __restrict__ active_list,
    const int* __restrict__ acount, float* __restrict__ out)
{
  __shared__ unsigned short Af[16*64*32];    // [kc][row 64][32k] = 64 KB
  __shared__ unsigned short Bs[2][512*32];   // 64 KB
  __shared__ float part[8][64];
  __shared__ int seg_sh[3];
  int blk = blockIdx.x, tid = threadIdx.x, wid = tid >> 6, lane = tid & 63;

  // ---- baseline slice: 128 rows per block, write rows with rgate==0 ----
  if (tid < 128){
    int gr = blk*128 + tid;
    float rgv = rgate_a[gr];
    if (rgv == 0.f){
      int b = gr >> 12;
      float csum = cb2[0];
      #pragma unroll
      for (int c = 0; c < 8; ++c) csum += coarse_part[b*8 + c];
      float cs = 0.2f * tanhf(csum);
      float m = um[gr] > 0 ? 1.f : 0.f;
      float sealed = sm[gr] > 0 ? 1.f : 0.f;
      float sil = (zm[gr] > 0 ? 1.f : 0.f) * m;
      float commit = m * sealed;
      float speech = commit * (1.f - sil);
      float silc = commit * sil;
      float g = (grate[b] - rate_seq[gr] + cs) * commit;
      out[gr] = fminf(fmaxf(g, -1.2f), 1.2f) * speech
              + fminf(fmaxf(g, -0.35f), 0.35f) * silc;
    }
  }

  const char* wbase = (const char*)wqt;
  auto stageB = [&](unsigned short* dstbuf, int kc){
    int k0b = kc * 64;  // byte offset into each 1024B (512-elem bf16) row
    #pragma unroll
    for (int i = 0; i < 4; ++i){
      int j = wid*4 + i;                      // wave wid owns B-rows 64wid..64wid+63
      int n = j*16 + (lane >> 2);
      int slot = (lane & 3) ^ ((n >> 1) & 3);
      const char* src = wbase + (long)n*1024 + k0b + slot*16;
      char* dst = (char*)dstbuf + j*1024 + (lane << 4);
      __builtin_amdgcn_global_load_lds(
          (const __attribute__((address_space(1))) void*)src,
          (__attribute__((address_space(3))) void*)dst, 16, 0, 0);
    }
  };

  // ---- gemm tiles (BM=64): p = blk, blk+256, ... ----
  for (int p = blk; ; p += 256){
    if (tid == 0){
      int cum = 0, sb = -1, slo = 0, scnt = 0;
      #pragma unroll
      for (int b = 0; b < BB; ++b){
        int c = acount[b];
        int nb = (c + 63) >> 6;
        if (sb < 0 && p < cum + nb){ sb = b; slo = (p - cum) * 64; scnt = c; }
        cum += nb;
      }
      seg_sh[0] = sb; seg_sh[1] = slo; seg_sh[2] = scnt;
    }
    __syncthreads();
    int seg_b = seg_sh[0], seg_lo = seg_sh[1], seg_cnt = seg_sh[2];
    if (seg_b < 0) break;
    const int* alist = active_list + seg_b*TT;

    float csum = cb2[0];
    #pragma unroll
    for (int c = 0; c < 8; ++c) csum += coarse_part[seg_b*8 + c];
    float cs = 0.2f * tanhf(csum);
    float grc = grate[seg_b];

    stageB(&Bs[0][0], 0);   // latency hides under A-build

    // ---- build A tile: 1024 (row,chunk) pairs, 2 per thread ----
    #pragma unroll
    for (int j = 0; j < 2; ++j){
      int idx = tid + j*512;
      int rr = idx >> 4, kc = idx & 15;
      int q = seg_lo + rr; if (q > seg_cnt-1) q = seg_cnt-1;
      int gr = alist[q];
      float la = la_g[gr], rate = rate_seq[gr];
      float sepv = sep[gr], edgev = edge[gr];
      int k0 = kc * 32;
      const float* er = emb + (long)content[gr]*DD + k0;
      union { bf16x8 v[4]; unsigned short h[32]; } pk;
      #pragma unroll
      for (int i = 0; i < 32; i += 4){
        float4 e  = *(const float4*)(er + i);
        float4 w0 = *(const float4*)(fW + 0*DD + k0 + i);
        float4 w1 = *(const float4*)(fW + 1*DD + k0 + i);
        float4 w3 = *(const float4*)(fW + 3*DD + k0 + i);
        float4 w4 = *(const float4*)(fW + 4*DD + k0 + i);
        float4 bb = *(const float4*)(fb + k0 + i);
        pk.h[i+0] = f2bf(gelu_f(e.x + la*w0.x + rate*w1.x + sepv*w3.x + edgev*w4.x + bb.x));
        pk.h[i+1] = f2bf(gelu_f(e.y + la*w0.y + rate*w1.y + sepv*w3.y + edgev*w4.y + bb.y));
        pk.h[i+2] = f2bf(gelu_f(e.z + la*w0.z + rate*w1.z + sepv*w3.z + edgev*w4.z + bb.z));
        pk.h[i+3] = f2bf(gelu_f(e.w + la*w0.w + rate*w1.w + sepv*w3.w + edgev*w4.w + bb.w));
      }
      int c = (rr >> 1) & 3;
      char* abase = (char*)Af + kc*4096 + rr*64;
      #pragma unroll
      for (int s = 0; s < 4; ++s)
        *(bf16x8*)(abase + ((s ^ c) << 4)) = pk.v[s];
    }
    __syncthreads();   // Af visible to all waves (also drains stage(0))

    f32x4 acc[4][4];
    #pragma unroll
    for (int i = 0; i < 4; ++i)
      #pragma unroll
      for (int j = 0; j < 4; ++j) acc[i][j] = (f32x4){0.f,0.f,0.f,0.f};

    int rgp = lane >> 4, li = lane & 15;
    #pragma unroll
    for (int kc = 0; kc < 16; ++kc){
      // issue next chunk into the other buffer (per-wave-disjoint B rows)
      if (kc < 15) stageB(&Bs[(kc+1)&1][0], kc+1);
      // per-wave wait: kc's 4 loads done (kc+1's may stay in flight)
      if (kc < 15) asm volatile("s_waitcnt vmcnt(4)" ::: "memory");
      else         asm volatile("s_waitcnt vmcnt(0)" ::: "memory");
      const char* bsb = (const char*)&Bs[kc&1][0];
      bf16x8 a[4], bb[4];
      #pragma unroll
      for (int mt = 0; mt < 4; ++mt){
        int row = mt*16 + li;
        int slot = rgp ^ ((row >> 1) & 3);
        a[mt] = *(const bf16x8*)((const char*)Af + kc*4096 + row*64 + (slot << 4));
      }
      #pragma unroll
      for (int nt = 0; nt < 4; ++nt){
        int n = wid*64 + nt*16 + li;
        int slot = rgp ^ ((n >> 1) & 3);
        bb[nt] = *(const bf16x8*)(bsb + n*64 + slot*16);
      }
      #pragma unroll
      for (int mt = 0; mt < 4; ++mt)
        #pragma unroll
        for (int nt = 0; nt < 4; ++nt)
          acc[mt][nt] = __builtin_amdgcn_mfma_f32_16x16x32_bf16(a[mt], bb[nt], acc[mt][nt], 0, 0, 0);
    }

    // epilogue: h = gelu(y + s_vec[b] + gterm*wg + b1); dot with res_W2
    float svv[4], wgv[4], b1v[4], w2v[4];
    #pragma unroll
    for (int nt = 0; nt < 4; ++nt){
      int j = wid*64 + nt*16 + li;
      svv[nt] = s_vec[seg_b*DD + j];
      wgv[nt] = rW1[1024*DD + j];    // wg = res_W1 row 1024
      b1v[nt] = rb1[j];
      w2v[nt] = rW2[j];
    }
    #pragma unroll
    for (int mt = 0; mt < 4; ++mt){
      #pragma unroll
      for (int r = 0; r < 4; ++r){
        int row = mt*16 + rgp*4 + r;
        int q = seg_lo + row; if (q > seg_cnt-1) q = seg_cnt-1;
        int gr = alist[q];
        float gt = grc - rate_seq[gr] + cs;    // active rows: commit==1
        float s = 0.f;
        #pragma unroll
        for (int nt = 0; nt < 4; ++nt){
          float y = acc[mt][nt][r] + svv[nt] + gt*wgv[nt] + b1v[nt];
          s += gelu_f(y) * w2v[nt];
        }
        s += __shfl_xor(s, 1, 64);
        s += __shfl_xor(s, 2, 64);
        s += __shfl_xor(s, 4, 64);
        s += __shfl_xor(s, 8, 64);
        if (li == 0) part[wid][row] = s;
      }
    }
    __syncthreads();
    if (tid < 64){
      int q = seg_lo + tid;
      if (q < seg_cnt){
        int gr = alist[q];
        float s = 0.f;
        #pragma unroll
        for (int w = 0; w < 8; ++w) s += part[w][tid];
        float resid = 0.35f * tanhf(s + rb2[0]) * rgate_a[gr];
        float g = grc - rate_seq[gr] + cs;
        // active rows: speech==1, sil_commit==0
        out[gr] = fminf(fmaxf(g + resid, -1.2f), 1.2f);
      }
    }
    __syncthreads();   // protect Af/part before a possible next tile
  }
}

extern "C" void kernel_launch(void* const* d_in, const int* in_sizes, int n_in,
                              void* d_out, int out_size, void* d_ws, size_t ws_size,
                              hipStream_t stream)
{
  const int*   content = (const int*)  d_in[0];
  const float* la      = (const float*)d_in[1];
  const int*   um      = (const int*)  d_in[2];
  const int*   smk     = (const int*)  d_in[3];
  const int*   zm      = (const int*)  d_in[4];
  const float* sep     = (const float*)d_in[5];
  const float* edge    = (const float*)d_in[6];
  const float* stab    = (const float*)d_in[7];
  const float* grate   = (const float*)d_in[8];
  const float* lre     = (const float*)d_in[9];
  const float* spk_e   = (const float*)d_in[10];
  const float* emb     = (const float*)d_in[11];
  const float* fW      = (const float*)d_in[12];
  const float* fb      = (const float*)d_in[13];
  const float* spk_W   = (const float*)d_in[14];
  const float* spk_b   = (const float*)d_in[15];
  const float* cW1     = (const float*)d_in[16];
  const float* cb1     = (const float*)d_in[17];
  const float* cW2     = (const float*)d_in[18];
  const float* cb2     = (const float*)d_in[19];
  const float* rW1     = (const float*)d_in[20];
  const float* rb1     = (const float*)d_in[21];
  const float* rW2     = (const float*)d_in[22];
  const float* rb2     = (const float*)d_in[23];

  char* w = (char*)d_ws;
  unsigned short* wsWqT = (unsigned short*)(w);                 // 524288 B
  size_t off = 524288;
  float* rate_seq = (float*)(w + off); off += MM*4;
  float* rgate_a  = (float*)(w + off); off += MM*4;
  int*   active_list = (int*)(w + off); off += MM*4;
  float* s_vec    = (float*)(w + off); off += BB*DD*4;
  float* coarse_part = (float*)(w + off); off += 64*4;
  int*   acount   = (int*)(w + off); off += 256;

  pre_kernel<<<136, 512, 0, stream>>>(spk_e, spk_W, spk_b, rW1, cW1, cb1, cW2,
      grate, la, um, smk, zm, stab, lre,
      wsWqT, s_vec, coarse_part, rate_seq, rgate_a, active_list, acount);
  main_kernel<<<256, 512, 0, stream>>>(content, la, sep, edge, emb, fW, fb,
      rate_seq, wsWqT, s_vec, rW1, rb1, rW2, rb2, grate, coarse_part, cb2,
      um, smk, zm, rgate_a, active_list, acount, (float*)d_out);
}

// Round 12
// 69.370 us; speedup vs baseline: 1.5662x; 1.5662x over previous
//
#include <hip/hip_runtime.h>
#include <hip/hip_bf16.h>

// ---- problem constants ----
#define BB 8
#define TT 4096
#define DD 512
#define MM (BB*TT)          // 32768 rows
#define DECAYF 0.95f
#define OMDECAYF (1.0f - 0.95f)

typedef __attribute__((ext_vector_type(8))) short bf16x8;
typedef __attribute__((ext_vector_type(4))) float f32x4;

__device__ __forceinline__ float gelu_f(float x){
  return 0.5f * x * (1.0f + erff(x * 0.70710678118654752f));
}

__device__ __forceinline__ unsigned short f2bf(float x){
  unsigned u = __float_as_uint(x);
  unsigned r = (u + 0x7FFFu + ((u >> 16) & 1u)) >> 16;
  return (unsigned short)r;
}

// ====== K1: blocks 0-63  {spk_ctx coalesced GEMV + s_vec/coarse chunk}
//            blocks 64-127 transpose | blocks 128-135 scan+compaction ========
__global__ __launch_bounds__(512) void pre_kernel(
    const float* __restrict__ spk_embed, const float* __restrict__ spk_W,
    const float* __restrict__ spk_b, const float* __restrict__ rW1,
    const float* __restrict__ cW1, const float* __restrict__ cb1,
    const float* __restrict__ cW2, const float* __restrict__ grate,
    const float* __restrict__ la_g, const int* __restrict__ um,
    const int* __restrict__ sm, const int* __restrict__ zm,
    const float* __restrict__ stab_g, const float* __restrict__ lre,
    unsigned short* __restrict__ wqt, float* __restrict__ s_vec,
    float* __restrict__ coarse_part,
    float* __restrict__ rate_seq, float* __restrict__ rgate_a,
    int* __restrict__ active_list, int* __restrict__ acount)
{
  __shared__ float se[DD];
  __shared__ float scf[DD];
  __shared__ float red1[8][64];
  __shared__ float red2[8][64];
  __shared__ float tile[64][65];
  __shared__ float wAg[8], wBg[8], wSg[8];
  __shared__ int wcnt[8];
  int blk = blockIdx.x, t = threadIdx.x;
  int lane = t & 63, wid = t >> 6;

  if (blk < 64){
    // ---- phase A: full spk_ctx[b] via thread-per-column, COALESCED reads ----
    int b = blk >> 3, d0 = (blk & 7) * 64;
    se[t] = spk_embed[b*DD + t];
    __syncthreads();
    {
      float a = spk_b[t];
      const float* wp = spk_W + t;
      #pragma unroll 8
      for (int k = 0; k < DD; ++k) a = fmaf(se[k], wp[(long)k*DD], a);
      scf[t] = tanhf(a);
    }
    __syncthreads();
    // ---- phase B: s_vec chunk + coarse hidden partial (k-sliced waves) ----
    int dl = lane, ks = wid;
    float a1 = 0.f, a2 = 0.f;
    const float* wsp = rW1 + (long)(DD + ks*64)*DD + d0 + dl;   // Ws = res_W1[D:2D]
    const float* wcp = cW1 + (long)(ks*64)*DD + d0 + dl;
    #pragma unroll 4
    for (int k = 0; k < 64; ++k){
      float s = scf[ks*64 + k];
      a1 += s * wsp[(long)k*DD];
      a2 += s * wcp[(long)k*DD];
    }
    red1[ks][dl] = a1; red2[ks][dl] = a2;
    __syncthreads();
    if (t < 64){
      int d = d0 + t;
      float s1 = 0.f;
      float s2 = cb1[d] + grate[b] * cW1[(long)DD*DD + d];   // row 512 = grc coeff
      #pragma unroll
      for (int i = 0; i < 8; ++i){ s1 += red1[i][t]; s2 += red2[i][t]; }
      s_vec[b*DD + d] = s1;
      float hv = gelu_f(s2) * cW2[d];
      #pragma unroll
      for (int sh = 1; sh < 64; sh <<= 1) hv += __shfl_xor(hv, sh, 64);
      if (t == 0) coarse_part[blk] = hv;
    }
    return;
  }
  if (blk < 128){
    // ---- transpose Wq (k-major f32) -> WqT (n-major bf16) ----
    int tb = blk - 64;
    int nb = (tb & 7) * 64, kb = (tb >> 3) * 64;
    int tx = t & 63, ty = t >> 6;
    #pragma unroll
    for (int i = 0; i < 8; ++i){
      int k = ty + i*8;
      tile[k][tx] = rW1[(long)(kb + k)*DD + nb + tx];
    }
    __syncthreads();
    #pragma unroll
    for (int i = 0; i < 8; ++i){
      int nl = ty + i*8;
      wqt[(long)(nb + nl)*DD + kb + tx] = f2bf(tile[tx][nl]);
    }
    return;
  }

  // ---- scan: rate_seq + rgate + segmented compaction (batch b) ----
  int b = blk - 128;
  int base = b*TT + t*8;
  float4 la0 = *(const float4*)(la_g + base);
  float4 la1 = *(const float4*)(la_g + base + 4);
  int4 u0 = *(const int4*)(um + base), u1 = *(const int4*)(um + base + 4);
  int4 s0 = *(const int4*)(sm + base), s1 = *(const int4*)(sm + base + 4);
  int4 z0 = *(const int4*)(zm + base), z1 = *(const int4*)(zm + base + 4);
  float4 st0 = *(const float4*)(stab_g + base), st1 = *(const float4*)(stab_g + base + 4);
  float lav[8] = {la0.x,la0.y,la0.z,la0.w,la1.x,la1.y,la1.z,la1.w};
  int uv[8] = {u0.x,u0.y,u0.z,u0.w,u1.x,u1.y,u1.z,u1.w};
  int sv[8] = {s0.x,s0.y,s0.z,s0.w,s1.x,s1.y,s1.z,s1.w};
  int zv[8] = {z0.x,z0.y,z0.z,z0.w,z1.x,z1.y,z1.z,z1.w};
  float stv_[8] = {st0.x,st0.y,st0.z,st0.w,st1.x,st1.y,st1.z,st1.w};
  float spv[8], stv[8];

  float A = 1.f, Bv = 0.f, S = 0.f;
  #pragma unroll
  for (int i = 0; i < 8; ++i){
    float m = uv[i] > 0 ? 1.f : 0.f;
    float sealed = sv[i] > 0 ? 1.f : 0.f;
    float sil = (zv[i] > 0 ? 1.f : 0.f) * m;
    float speech = (m * sealed) * (1.f - sil);
    spv[i] = speech;
    stv[i] = fminf(fmaxf(stv_[i], 0.f), 1.f) * m;
    if (speech > 0.f){
      Bv = DECAYF*Bv + OMDECAYF*lav[i];
      A *= DECAYF;
      S += 1.f;
    }
  }
  #pragma unroll
  for (int d = 1; d < 64; d <<= 1){
    float Au = __shfl_up(A, d, 64);
    float Bu = __shfl_up(Bv, d, 64);
    float Su = __shfl_up(S, d, 64);
    if (lane >= d){ Bv = A*Bu + Bv; A = A*Au; S += Su; }
  }
  if (lane == 63){ wAg[wid] = A; wBg[wid] = Bv; wSg[wid] = S; }
  float Ale = __shfl_up(A, 1, 64), Ble = __shfl_up(Bv, 1, 64), Sle = __shfl_up(S, 1, 64);
  if (lane == 0){ Ale = 1.f; Ble = 0.f; Sle = 0.f; }
  __syncthreads();
  float Awp = 1.f, Bwp = 0.f, Swp = 0.f;
  for (int w = 0; w < wid; ++w){
    Bwp = wAg[w]*Bwp + wBg[w];
    Awp = wAg[w]*Awp;
    Swp += wSg[w];
  }
  float Bex = Ale*Bwp + Ble;
  float Aex = Ale*Awp;
  float Sex = Swp + Sle;

  float rate = Aex*lre[b] + Bex;
  float ps = Sex;
  float ro[8], rg[8];
  #pragma unroll
  for (int i = 0; i < 8; ++i){
    ro[i] = rate;
    float cold = fminf(ps * 0.5f, 1.f);                        // COLD_RUNS=2
    float shortg = fminf(fmaxf(expf(lav[i]) - 1.f, 0.f), 1.f); // MIN_DUR=2
    rg[i] = cold * shortg * stv[i] * spv[i];
    if (spv[i] > 0.f){
      rate = DECAYF*rate + OMDECAYF*lav[i];
      ps += 1.f;
    }
  }
  *(float4*)(rate_seq + base)     = make_float4(ro[0],ro[1],ro[2],ro[3]);
  *(float4*)(rate_seq + base + 4) = make_float4(ro[4],ro[5],ro[6],ro[7]);
  *(float4*)(rgate_a + base)      = make_float4(rg[0],rg[1],rg[2],rg[3]);
  *(float4*)(rgate_a + base + 4)  = make_float4(rg[4],rg[5],rg[6],rg[7]);

  int nact = 0;
  #pragma unroll
  for (int i = 0; i < 8; ++i) nact += (rg[i] != 0.f) ? 1 : 0;
  int inc = nact;
  #pragma unroll
  for (int d = 1; d < 64; d <<= 1){
    int u = __shfl_up(inc, d, 64);
    if (lane >= d) inc += u;
  }
  int myex = inc - nact;
  if (lane == 63) wcnt[wid] = inc;
  __syncthreads();
  int wbase = 0;
  for (int w = 0; w < wid; ++w) wbase += wcnt[w];
  int pos = wbase + myex;
  int* alist = active_list + b*TT;
  #pragma unroll
  for (int i = 0; i < 8; ++i){
    if (rg[i] != 0.f) alist[pos++] = base + i;
  }
  if (t == 0){
    int total = 0;
    #pragma unroll
    for (int w = 0; w < 8; ++w) total += wcnt[w];
    acount[b] = total;
  }
}

// ====== K2: persistent 256 blocks: baseline slice, then BM=32 gemm tiles =====
// BM=32, BN=512, BK=32, 8 waves; 2-buffer B staging, NO per-step barriers:
// wave wid stages AND reads only B-rows [64*wid, 64*wid+64) -> per-wave
// counted vmcnt(4) is the only K-loop sync (Af: one barrier after build).
// BM=32 keeps acc at 32 VGPR/thread (R5/R6 measured 64 VGPR total, no spill).
__global__ __launch_bounds__(512) void main_kernel(
    const int* __restrict__ content, const float* __restrict__ la_g,
    const float* __restrict__ sep, const float* __restrict__ edge,
    const float* __restrict__ emb, const float* __restrict__ fW,
    const float* __restrict__ fb, const float* __restrict__ rate_seq,
    const unsigned short* __restrict__ wqt,
    const float* __restrict__ s_vec, const float* __restrict__ rW1,
    const float* __restrict__ rb1, const float* __restrict__ rW2,
    const float* __restrict__ rb2, const float* __restrict__ grate,
    const float* __restrict__ coarse_part, const float* __restrict__ cb2,
    const int* __restrict__ um, const int* __restrict__ sm,
    const int* __restrict__ zm,
    const float* __restrict__ rgate_a, const int* __restrict__ active_list,
    const int* __restrict__ acount, float* __restrict__ out)
{
  __shared__ unsigned short Af[16*32*32];    // [kc][row 32][32k] = 32 KB
  __shared__ unsigned short Bs[2][512*32];   // 64 KB
  __shared__ float part[8][32];
  __shared__ int seg_sh[3];
  int blk = blockIdx.x, tid = threadIdx.x, wid = tid >> 6, lane = tid & 63;

  // ---- baseline slice: 128 rows per block, write rows with rgate==0 ----
  if (tid < 128){
    int gr = blk*128 + tid;
    float rgv = rgate_a[gr];
    if (rgv == 0.f){
      int b = gr >> 12;
      float csum = cb2[0];
      #pragma unroll
      for (int c = 0; c < 8; ++c) csum += coarse_part[b*8 + c];
      float cs = 0.2f * tanhf(csum);
      float m = um[gr] > 0 ? 1.f : 0.f;
      float sealed = sm[gr] > 0 ? 1.f : 0.f;
      float sil = (zm[gr] > 0 ? 1.f : 0.f) * m;
      float commit = m * sealed;
      float speech = commit * (1.f - sil);
      float silc = commit * sil;
      float g = (grate[b] - rate_seq[gr] + cs) * commit;
      out[gr] = fminf(fmaxf(g, -1.2f), 1.2f) * speech
              + fminf(fmaxf(g, -0.35f), 0.35f) * silc;
    }
  }

  const char* wbase = (const char*)wqt;
  auto stageB = [&](unsigned short* dstbuf, int kc){
    int k0b = kc * 64;  // byte offset into each 1024B (512-elem bf16) row
    #pragma unroll
    for (int i = 0; i < 4; ++i){
      int j = wid*4 + i;                      // wave wid owns B-rows 64wid..64wid+63
      int n = j*16 + (lane >> 2);
      int slot = (lane & 3) ^ ((n >> 1) & 3);
      const char* src = wbase + (long)n*1024 + k0b + slot*16;
      char* dst = (char*)dstbuf + j*1024 + (lane << 4);
      __builtin_amdgcn_global_load_lds(
          (const __attribute__((address_space(1))) void*)src,
          (__attribute__((address_space(3))) void*)dst, 16, 0, 0);
    }
  };

  // ---- gemm tiles (BM=32): p = blk, blk+256, ... ----
  for (int p = blk; ; p += 256){
    if (tid == 0){
      int cum = 0, sb = -1, slo = 0, scnt = 0;
      #pragma unroll
      for (int b = 0; b < BB; ++b){
        int c = acount[b];
        int nb = (c + 31) >> 5;
        if (sb < 0 && p < cum + nb){ sb = b; slo = (p - cum) * 32; scnt = c; }
        cum += nb;
      }
      seg_sh[0] = sb; seg_sh[1] = slo; seg_sh[2] = scnt;
    }
    __syncthreads();
    int seg_b = seg_sh[0], seg_lo = seg_sh[1], seg_cnt = seg_sh[2];
    if (seg_b < 0) break;
    const int* alist = active_list + seg_b*TT;

    float csum = cb2[0];
    #pragma unroll
    for (int c = 0; c < 8; ++c) csum += coarse_part[seg_b*8 + c];
    float cs = 0.2f * tanhf(csum);
    float grc = grate[seg_b];

    stageB(&Bs[0][0], 0);   // latency hides under A-build

    // ---- build A tile: 512 (row,chunk) pairs, 1 per thread ----
    {
      int rr = tid >> 4, kc = tid & 15;
      int q = seg_lo + rr; if (q > seg_cnt-1) q = seg_cnt-1;
      int gr = alist[q];
      float la = la_g[gr], rate = rate_seq[gr];
      float sepv = sep[gr], edgev = edge[gr];
      int k0 = kc * 32;
      const float* er = emb + (long)content[gr]*DD + k0;
      union { bf16x8 v[4]; unsigned short h[32]; } pk;
      #pragma unroll
      for (int i = 0; i < 32; i += 4){
        float4 e  = *(const float4*)(er + i);
        float4 w0 = *(const float4*)(fW + 0*DD + k0 + i);
        float4 w1 = *(const float4*)(fW + 1*DD + k0 + i);
        float4 w3 = *(const float4*)(fW + 3*DD + k0 + i);
        float4 w4 = *(const float4*)(fW + 4*DD + k0 + i);
        float4 bb = *(const float4*)(fb + k0 + i);
        pk.h[i+0] = f2bf(gelu_f(e.x + la*w0.x + rate*w1.x + sepv*w3.x + edgev*w4.x + bb.x));
        pk.h[i+1] = f2bf(gelu_f(e.y + la*w0.y + rate*w1.y + sepv*w3.y + edgev*w4.y + bb.y));
        pk.h[i+2] = f2bf(gelu_f(e.z + la*w0.z + rate*w1.z + sepv*w3.z + edgev*w4.z + bb.z));
        pk.h[i+3] = f2bf(gelu_f(e.w + la*w0.w + rate*w1.w + sepv*w3.w + edgev*w4.w + bb.w));
      }
      int c = (rr >> 1) & 3;
      char* abase = (char*)Af + kc*2048 + rr*64;
      #pragma unroll
      for (int s = 0; s < 4; ++s)
        *(bf16x8*)(abase + ((s ^ c) << 4)) = pk.v[s];
    }
    __syncthreads();   // Af visible to all waves (also drains stage(0))

    f32x4 acc[2][4];
    #pragma unroll
    for (int i = 0; i < 2; ++i)
      #pragma unroll
      for (int j = 0; j < 4; ++j) acc[i][j] = (f32x4){0.f,0.f,0.f,0.f};

    int rgp = lane >> 4, li = lane & 15;
    #pragma unroll
    for (int kc = 0; kc < 16; ++kc){
      // issue next chunk into the other buffer (per-wave-disjoint B rows)
      if (kc < 15) stageB(&Bs[(kc+1)&1][0], kc+1);
      // per-wave wait: kc's 4 loads done (kc+1's may stay in flight)
      if (kc < 15) asm volatile("s_waitcnt vmcnt(4)" ::: "memory");
      else         asm volatile("s_waitcnt vmcnt(0)" ::: "memory");
      const char* bsb = (const char*)&Bs[kc&1][0];
      bf16x8 a[2], bb[4];
      #pragma unroll
      for (int mt = 0; mt < 2; ++mt){
        int row = mt*16 + li;
        int slot = rgp ^ ((row >> 1) & 3);
        a[mt] = *(const bf16x8*)((const char*)Af + kc*2048 + row*64 + (slot << 4));
      }
      #pragma unroll
      for (int nt = 0; nt < 4; ++nt){
        int n = wid*64 + nt*16 + li;
        int slot = rgp ^ ((n >> 1) & 3);
        bb[nt] = *(const bf16x8*)(bsb + n*64 + slot*16);
      }
      #pragma unroll
      for (int mt = 0; mt < 2; ++mt)
        #pragma unroll
        for (int nt = 0; nt < 4; ++nt)
          acc[mt][nt] = __builtin_amdgcn_mfma_f32_16x16x32_bf16(a[mt], bb[nt], acc[mt][nt], 0, 0, 0);
    }

    // epilogue: h = gelu(y + s_vec[b] + gterm*wg + b1); dot with res_W2
    float svv[4], wgv[4], b1v[4], w2v[4];
    #pragma unroll
    for (int nt = 0; nt < 4; ++nt){
      int j = wid*64 + nt*16 + li;
      svv[nt] = s_vec[seg_b*DD + j];
      wgv[nt] = rW1[1024*DD + j];    // wg = res_W1 row 1024
      b1v[nt] = rb1[j];
      w2v[nt] = rW2[j];
    }
    #pragma unroll
    for (int mt = 0; mt < 2; ++mt){
      #pragma unroll
      for (int r = 0; r < 4; ++r){
        int row = mt*16 + rgp*4 + r;
        int q = seg_lo + row; if (q > seg_cnt-1) q = seg_cnt-1;
        int gr = alist[q];
        float gt = grc - rate_seq[gr] + cs;    // active rows: commit==1
        float s = 0.f;
        #pragma unroll
        for (int nt = 0; nt < 4; ++nt){
          float y = acc[mt][nt][r] + svv[nt] + gt*wgv[nt] + b1v[nt];
          s += gelu_f(y) * w2v[nt];
        }
        s += __shfl_xor(s, 1, 64);
        s += __shfl_xor(s, 2, 64);
        s += __shfl_xor(s, 4, 64);
        s += __shfl_xor(s, 8, 64);
        if (li == 0) part[wid][row] = s;
      }
    }
    __syncthreads();
    if (tid < 32){
      int q = seg_lo + tid;
      if (q < seg_cnt){
        int gr = alist[q];
        float s = 0.f;
        #pragma unroll
        for (int w = 0; w < 8; ++w) s += part[w][tid];
        float resid = 0.35f * tanhf(s + rb2[0]) * rgate_a[gr];
        float g = grc - rate_seq[gr] + cs;
        // active rows: speech==1, sil_commit==0
        out[gr] = fminf(fmaxf(g + resid, -1.2f), 1.2f);
      }
    }
    __syncthreads();   // protect Af/part before a possible next tile
  }
}

extern "C" void kernel_launch(void* const* d_in, const int* in_sizes, int n_in,
                              void* d_out, int out_size, void* d_ws, size_t ws_size,
                              hipStream_t stream)
{
  const int*   content = (const int*)  d_in[0];
  const float* la      = (const float*)d_in[1];
  const int*   um      = (const int*)  d_in[2];
  const int*   smk     = (const int*)  d_in[3];
  const int*   zm      = (const int*)  d_in[4];
  const float* sep     = (const float*)d_in[5];
  const float* edge    = (const float*)d_in[6];
  const float* stab    = (const float*)d_in[7];
  const float* grate   = (const float*)d_in[8];
  const float* lre     = (const float*)d_in[9];
  const float* spk_e   = (const float*)d_in[10];
  const float* emb     = (const float*)d_in[11];
  const float* fW      = (const float*)d_in[12];
  const float* fb      = (const float*)d_in[13];
  const float* spk_W   = (const float*)d_in[14];
  const float* spk_b   = (const float*)d_in[15];
  const float* cW1     = (const float*)d_in[16];
  const float* cb1     = (const float*)d_in[17];
  const float* cW2     = (const float*)d_in[18];
  const float* cb2     = (const float*)d_in[19];
  const float* rW1     = (const float*)d_in[20];
  const float* rb1     = (const float*)d_in[21];
  const float* rW2     = (const float*)d_in[22];
  const float* rb2     = (const float*)d_in[23];

  char* w = (char*)d_ws;
  unsigned short* wsWqT = (unsigned short*)(w);                 // 524288 B
  size_t off = 524288;
  float* rate_seq = (float*)(w + off); off += MM*4;
  float* rgate_a  = (float*)(w + off); off += MM*4;
  int*   active_list = (int*)(w + off); off += MM*4;
  float* s_vec    = (float*)(w + off); off += BB*DD*4;
  float* coarse_part = (float*)(w + off); off += 64*4;
  int*   acount   = (int*)(w + off); off += 256;

  pre_kernel<<<136, 512, 0, stream>>>(spk_e, spk_W, spk_b, rW1, cW1, cb1, cW2,
      grate, la, um, smk, zm, stab, lre,
      wsWqT, s_vec, coarse_part, rate_seq, rgate_a, active_list, acount);
  main_kernel<<<256, 512, 0, stream>>>(content, la, sep, edge, emb, fW, fb,
      rate_seq, wsWqT, s_vec, rW1, rb1, rW2, rb2, grate, coarse_part, cb2,
      um, smk, zm, rgate_a, active_list, acount, (float*)d_out);
}

// Round 14
// 50.793 us; speedup vs baseline: 2.1390x; 1.3658x over previous
//
#include <hip/hip_runtime.h>
#include <hip/hip_bf16.h>

// ---- problem constants ----
#define BB 8
#define TT 4096
#define DD 512
#define MM (BB*TT)          // 32768 rows
#define DECAYF 0.95f
#define OMDECAYF (1.0f - 0.95f)

typedef __attribute__((ext_vector_type(8))) short bf16x8;
typedef __attribute__((ext_vector_type(4))) float f32x4;

__device__ __forceinline__ float gelu_f(float x){
  return 0.5f * x * (1.0f + erff(x * 0.70710678118654752f));
}

__device__ __forceinline__ unsigned short f2bf(float x){
  unsigned u = __float_as_uint(x);
  unsigned r = (u + 0x7FFFu + ((u >> 16) & 1u)) >> 16;
  return (unsigned short)r;
}

// ====== K1: blocks 0-63 prep1 (k-sliced) | 64-127 transpose | 128-135 scan ====
__global__ __launch_bounds__(512) void pre_kernel(
    const float* __restrict__ spk_embed, const float* __restrict__ spk_W,
    const float* __restrict__ spk_b, const float* __restrict__ rW1,
    const float* __restrict__ la_g, const int* __restrict__ um,
    const int* __restrict__ sm, const int* __restrict__ zm,
    const float* __restrict__ stab_g, const float* __restrict__ lre,
    float* __restrict__ spk_ctx, unsigned short* __restrict__ wqt,
    float* __restrict__ rate_seq, float* __restrict__ rgate_a,
    int* __restrict__ active_list, int* __restrict__ acount)
{
  __shared__ float se[DD];
  __shared__ float red[8][64];
  __shared__ float tile[64][65];
  __shared__ float wAg[8], wBg[8], wSg[8];
  __shared__ int wcnt[8];
  int blk = blockIdx.x, t = threadIdx.x;
  int lane = t & 63, wid = t >> 6;

  if (blk < 64){
    // ---- prep1: spk_ctx = tanh(spk_embed @ spk_W + spk_b), k-sliced ----
    int b = blk >> 3, d0 = (blk & 7) * 64;
    int dl = lane, ks = wid;
    se[t] = spk_embed[b*DD + t];
    __syncthreads();
    float a = 0.f;
    const float* wp = spk_W + (long)(ks*64)*DD + d0 + dl;
    #pragma unroll 8
    for (int k = 0; k < 64; ++k) a += se[ks*64 + k] * wp[(long)k*DD];
    red[ks][dl] = a;
    __syncthreads();
    if (t < 64){
      float s = spk_b[d0 + t];
      #pragma unroll
      for (int i = 0; i < 8; ++i) s += red[i][t];
      spk_ctx[b*DD + d0 + t] = tanhf(s);
    }
    return;
  }
  if (blk < 128){
    // ---- transpose Wq (k-major f32) -> WqT (n-major bf16) ----
    int tb = blk - 64;
    int nb = (tb & 7) * 64, kb = (tb >> 3) * 64;
    int tx = t & 63, ty = t >> 6;
    #pragma unroll
    for (int i = 0; i < 8; ++i){
      int k = ty + i*8;
      tile[k][tx] = rW1[(long)(kb + k)*DD + nb + tx];
    }
    __syncthreads();
    #pragma unroll
    for (int i = 0; i < 8; ++i){
      int nl = ty + i*8;
      wqt[(long)(nb + nl)*DD + kb + tx] = f2bf(tile[tx][nl]);
    }
    return;
  }

  // ---- scan: rate_seq + rgate + segmented compaction (batch b) ----
  int b = blk - 128;
  int base = b*TT + t*8;
  float4 la0 = *(const float4*)(la_g + base);
  float4 la1 = *(const float4*)(la_g + base + 4);
  int4 u0 = *(const int4*)(um + base), u1 = *(const int4*)(um + base + 4);
  int4 s0 = *(const int4*)(sm + base), s1 = *(const int4*)(sm + base + 4);
  int4 z0 = *(const int4*)(zm + base), z1 = *(const int4*)(zm + base + 4);
  float4 st0 = *(const float4*)(stab_g + base), st1 = *(const float4*)(stab_g + base + 4);
  float lav[8] = {la0.x,la0.y,la0.z,la0.w,la1.x,la1.y,la1.z,la1.w};
  int uv[8] = {u0.x,u0.y,u0.z,u0.w,u1.x,u1.y,u1.z,u1.w};
  int sv[8] = {s0.x,s0.y,s0.z,s0.w,s1.x,s1.y,s1.z,s1.w};
  int zv[8] = {z0.x,z0.y,z0.z,z0.w,z1.x,z1.y,z1.z,z1.w};
  float stv_[8] = {st0.x,st0.y,st0.z,st0.w,st1.x,st1.y,st1.z,st1.w};
  float spv[8], stv[8];

  float A = 1.f, Bv = 0.f, S = 0.f;
  #pragma unroll
  for (int i = 0; i < 8; ++i){
    float m = uv[i] > 0 ? 1.f : 0.f;
    float sealed = sv[i] > 0 ? 1.f : 0.f;
    float sil = (zv[i] > 0 ? 1.f : 0.f) * m;
    float speech = (m * sealed) * (1.f - sil);
    spv[i] = speech;
    stv[i] = fminf(fmaxf(stv_[i], 0.f), 1.f) * m;
    if (speech > 0.f){
      Bv = DECAYF*Bv + OMDECAYF*lav[i];
      A *= DECAYF;
      S += 1.f;
    }
  }
  #pragma unroll
  for (int d = 1; d < 64; d <<= 1){
    float Au = __shfl_up(A, d, 64);
    float Bu = __shfl_up(Bv, d, 64);
    float Su = __shfl_up(S, d, 64);
    if (lane >= d){ Bv = A*Bu + Bv; A = A*Au; S += Su; }
  }
  if (lane == 63){ wAg[wid] = A; wBg[wid] = Bv; wSg[wid] = S; }
  float Ale = __shfl_up(A, 1, 64), Ble = __shfl_up(Bv, 1, 64), Sle = __shfl_up(S, 1, 64);
  if (lane == 0){ Ale = 1.f; Ble = 0.f; Sle = 0.f; }
  __syncthreads();
  float Awp = 1.f, Bwp = 0.f, Swp = 0.f;
  for (int w = 0; w < wid; ++w){
    Bwp = wAg[w]*Bwp + wBg[w];
    Awp = wAg[w]*Awp;
    Swp += wSg[w];
  }
  float Bex = Ale*Bwp + Ble;
  float Aex = Ale*Awp;
  float Sex = Swp + Sle;

  float rate = Aex*lre[b] + Bex;
  float ps = Sex;
  float ro[8], rg[8];
  #pragma unroll
  for (int i = 0; i < 8; ++i){
    ro[i] = rate;
    float cold = fminf(ps * 0.5f, 1.f);                        // COLD_RUNS=2
    float shortg = fminf(fmaxf(expf(lav[i]) - 1.f, 0.f), 1.f); // MIN_DUR=2
    rg[i] = cold * shortg * stv[i] * spv[i];
    if (spv[i] > 0.f){
      rate = DECAYF*rate + OMDECAYF*lav[i];
      ps += 1.f;
    }
  }
  *(float4*)(rate_seq + base)     = make_float4(ro[0],ro[1],ro[2],ro[3]);
  *(float4*)(rate_seq + base + 4) = make_float4(ro[4],ro[5],ro[6],ro[7]);
  *(float4*)(rgate_a + base)      = make_float4(rg[0],rg[1],rg[2],rg[3]);
  *(float4*)(rgate_a + base + 4)  = make_float4(rg[4],rg[5],rg[6],rg[7]);

  int nact = 0;
  #pragma unroll
  for (int i = 0; i < 8; ++i) nact += (rg[i] != 0.f) ? 1 : 0;
  int inc = nact;
  #pragma unroll
  for (int d = 1; d < 64; d <<= 1){
    int u = __shfl_up(inc, d, 64);
    if (lane >= d) inc += u;
  }
  int myex = inc - nact;
  if (lane == 63) wcnt[wid] = inc;
  __syncthreads();
  int wbase = 0;
  for (int w = 0; w < wid; ++w) wbase += wcnt[w];
  int pos = wbase + myex;
  int* alist = active_list + b*TT;
  #pragma unroll
  for (int i = 0; i < 8; ++i){
    if (rg[i] != 0.f) alist[pos++] = base + i;
  }
  if (t == 0){
    int total = 0;
    #pragma unroll
    for (int w = 0; w < 8; ++w) total += wcnt[w];
    acount[b] = total;
  }
}

// ====== K2: s_vec = spk_ctx@Ws ; coarse hidden partial dot (k-sliced) =========
__global__ __launch_bounds__(512) void prep2_kernel(
    const float* __restrict__ spk_ctx, const float* __restrict__ rW1,
    const float* __restrict__ cW1, const float* __restrict__ cb1,
    const float* __restrict__ cW2, const float* __restrict__ grate,
    float* __restrict__ s_vec, float* __restrict__ coarse_part)
{
  __shared__ float sc[DD];
  __shared__ float red1[8][64];
  __shared__ float red2[8][64];
  int blk = blockIdx.x;
  int b = blk >> 3, d0 = (blk & 7) * 64;
  int t = threadIdx.x, dl = t & 63, ks = t >> 6;
  sc[t] = spk_ctx[b*DD + t];
  __syncthreads();
  float a1 = 0.f, a2 = 0.f;
  const float* wsp = rW1 + (long)(DD + ks*64)*DD + d0 + dl;   // Ws = res_W1[D:2D]
  const float* wcp = cW1 + (long)(ks*64)*DD + d0 + dl;
  #pragma unroll 4
  for (int k = 0; k < 64; ++k){
    float s = sc[ks*64 + k];
    a1 += s * wsp[(long)k*DD];
    a2 += s * wcp[(long)k*DD];
  }
  red1[ks][dl] = a1; red2[ks][dl] = a2;
  __syncthreads();
  if (t < 64){
    int d = d0 + t;
    float s1 = 0.f;
    float s2 = cb1[d] + grate[b] * cW1[(long)DD*DD + d];   // row 512 = grc coeff
    #pragma unroll
    for (int i = 0; i < 8; ++i){ s1 += red1[i][t]; s2 += red2[i][t]; }
    s_vec[b*DD + d] = s1;
    float hv = gelu_f(s2) * cW2[d];
    #pragma unroll
    for (int sh = 1; sh < 64; sh <<= 1) hv += __shfl_xor(hv, sh, 64);
    if (t == 0) coarse_part[blk] = hv;
  }
}

// ====== K3: persistent 256 blocks: baseline slice, then BM=32 gemm tiles =====
// BM=32, BN=512, BK=32, 8 waves; 2-buffer B staging, NO per-step barriers:
// wave wid stages AND reads only B-rows [64*wid, 64*wid+64) -> per-wave
// counted vmcnt(4) is the only K-loop sync (Af: one barrier after build).
__global__ __launch_bounds__(512) void main_kernel(
    const int* __restrict__ content, const float* __restrict__ la_g,
    const float* __restrict__ sep, const float* __restrict__ edge,
    const float* __restrict__ emb, const float* __restrict__ fW,
    const float* __restrict__ fb, const float* __restrict__ rate_seq,
    const unsigned short* __restrict__ wqt,
    const float* __restrict__ s_vec, const float* __restrict__ rW1,
    const float* __restrict__ rb1, const float* __restrict__ rW2,
    const float* __restrict__ rb2, const float* __restrict__ grate,
    const float* __restrict__ coarse_part, const float* __restrict__ cb2,
    const int* __restrict__ um, const int* __restrict__ sm,
    const int* __restrict__ zm,
    const float* __restrict__ rgate_a, const int* __restrict__ active_list,
    const int* __restrict__ acount, float* __restrict__ out)
{
  __shared__ unsigned short Af[16*32*32];    // [kc][row 32][32k] = 32 KB
  __shared__ unsigned short Bs[2][512*32];   // 64 KB
  __shared__ float part[8][32];
  __shared__ int seg_sh[3];
  int blk = blockIdx.x, tid = threadIdx.x, wid = tid >> 6, lane = tid & 63;

  // ---- baseline slice: 128 rows per block, write rows with rgate==0 ----
  if (tid < 128){
    int gr = blk*128 + tid;
    float rgv = rgate_a[gr];
    if (rgv == 0.f){
      int b = gr >> 12;
      float csum = cb2[0];
      #pragma unroll
      for (int c = 0; c < 8; ++c) csum += coarse_part[b*8 + c];
      float cs = 0.2f * tanhf(csum);
      float m = um[gr] > 0 ? 1.f : 0.f;
      float sealed = sm[gr] > 0 ? 1.f : 0.f;
      float sil = (zm[gr] > 0 ? 1.f : 0.f) * m;
      float commit = m * sealed;
      float speech = commit * (1.f - sil);
      float silc = commit * sil;
      float g = (grate[b] - rate_seq[gr] + cs) * commit;
      out[gr] = fminf(fmaxf(g, -1.2f), 1.2f) * speech
              + fminf(fmaxf(g, -0.35f), 0.35f) * silc;
    }
  }

  const char* wbase = (const char*)wqt;
  auto stageB = [&](unsigned short* dstbuf, int kc){
    int k0b = kc * 64;  // byte offset into each 1024B (512-elem bf16) row
    #pragma unroll
    for (int i = 0; i < 4; ++i){
      int j = wid*4 + i;                      // wave wid owns B-rows 64wid..64wid+63
      int n = j*16 + (lane >> 2);
      int slot = (lane & 3) ^ ((n >> 1) & 3);
      const char* src = wbase + (long)n*1024 + k0b + slot*16;
      char* dst = (char*)dstbuf + j*1024 + (lane << 4);
      __builtin_amdgcn_global_load_lds(
          (const __attribute__((address_space(1))) void*)src,
          (__attribute__((address_space(3))) void*)dst, 16, 0, 0);
    }
  };

  // ---- gemm tiles (BM=32): p = blk, blk+256, ... ----
  for (int p = blk; ; p += 256){
    if (tid == 0){
      int cum = 0, sb = -1, slo = 0, scnt = 0;
      #pragma unroll
      for (int b = 0; b < BB; ++b){
        int c = acount[b];
        int nb = (c + 31) >> 5;
        if (sb < 0 && p < cum + nb){ sb = b; slo = (p - cum) * 32; scnt = c; }
        cum += nb;
      }
      seg_sh[0] = sb; seg_sh[1] = slo; seg_sh[2] = scnt;
    }
    __syncthreads();
    int seg_b = seg_sh[0], seg_lo = seg_sh[1], seg_cnt = seg_sh[2];
    if (seg_b < 0) break;
    const int* alist = active_list + seg_b*TT;

    float csum = cb2[0];
    #pragma unroll
    for (int c = 0; c < 8; ++c) csum += coarse_part[seg_b*8 + c];
    float cs = 0.2f * tanhf(csum);
    float grc = grate[seg_b];

    stageB(&Bs[0][0], 0);   // latency hides under A-build

    // ---- build A tile: 512 (row,chunk) pairs, 1 per thread ----
    {
      int rr = tid >> 4, kc = tid & 15;
      int q = seg_lo + rr; if (q > seg_cnt-1) q = seg_cnt-1;
      int gr = alist[q];
      float la = la_g[gr], rate = rate_seq[gr];
      float sepv = sep[gr], edgev = edge[gr];
      int k0 = kc * 32;
      const float* er = emb + (long)content[gr]*DD + k0;
      union { bf16x8 v[4]; unsigned short h[32]; } pk;
      #pragma unroll
      for (int i = 0; i < 32; i += 4){
        float4 e  = *(const float4*)(er + i);
        float4 w0 = *(const float4*)(fW + 0*DD + k0 + i);
        float4 w1 = *(const float4*)(fW + 1*DD + k0 + i);
        float4 w3 = *(const float4*)(fW + 3*DD + k0 + i);
        float4 w4 = *(const float4*)(fW + 4*DD + k0 + i);
        float4 bb = *(const float4*)(fb + k0 + i);
        pk.h[i+0] = f2bf(gelu_f(e.x + la*w0.x + rate*w1.x + sepv*w3.x + edgev*w4.x + bb.x));
        pk.h[i+1] = f2bf(gelu_f(e.y + la*w0.y + rate*w1.y + sepv*w3.y + edgev*w4.y + bb.y));
        pk.h[i+2] = f2bf(gelu_f(e.z + la*w0.z + rate*w1.z + sepv*w3.z + edgev*w4.z + bb.z));
        pk.h[i+3] = f2bf(gelu_f(e.w + la*w0.w + rate*w1.w + sepv*w3.w + edgev*w4.w + bb.w));
      }
      int c = (rr >> 1) & 3;
      char* abase = (char*)Af + kc*2048 + rr*64;
      #pragma unroll
      for (int s = 0; s < 4; ++s)
        *(bf16x8*)(abase + ((s ^ c) << 4)) = pk.v[s];
    }
    __syncthreads();   // Af visible to all waves (also drains stage(0))

    f32x4 acc[2][4];
    #pragma unroll
    for (int i = 0; i < 2; ++i)
      #pragma unroll
      for (int j = 0; j < 4; ++j) acc[i][j] = (f32x4){0.f,0.f,0.f,0.f};

    int rgp = lane >> 4, li = lane & 15;
    #pragma unroll
    for (int kc = 0; kc < 16; ++kc){
      // issue next chunk into the other buffer (per-wave-disjoint B rows)
      if (kc < 15) stageB(&Bs[(kc+1)&1][0], kc+1);
      // per-wave wait: kc's 4 loads done (kc+1's may stay in flight)
      if (kc < 15) asm volatile("s_waitcnt vmcnt(4)" ::: "memory");
      else         asm volatile("s_waitcnt vmcnt(0)" ::: "memory");
      const char* bsb = (const char*)&Bs[kc&1][0];
      bf16x8 a[2], bb[4];
      #pragma unroll
      for (int mt = 0; mt < 2; ++mt){
        int row = mt*16 + li;
        int slot = rgp ^ ((row >> 1) & 3);
        a[mt] = *(const bf16x8*)((const char*)Af + kc*2048 + row*64 + (slot << 4));
      }
      #pragma unroll
      for (int nt = 0; nt < 4; ++nt){
        int n = wid*64 + nt*16 + li;
        int slot = rgp ^ ((n >> 1) & 3);
        bb[nt] = *(const bf16x8*)(bsb + n*64 + slot*16);
      }
      #pragma unroll
      for (int mt = 0; mt < 2; ++mt)
        #pragma unroll
        for (int nt = 0; nt < 4; ++nt)
          acc[mt][nt] = __builtin_amdgcn_mfma_f32_16x16x32_bf16(a[mt], bb[nt], acc[mt][nt], 0, 0, 0);
    }

    // epilogue: h = gelu(y + s_vec[b] + gterm*wg + b1); dot with res_W2
    float svv[4], wgv[4], b1v[4], w2v[4];
    #pragma unroll
    for (int nt = 0; nt < 4; ++nt){
      int j = wid*64 + nt*16 + li;
      svv[nt] = s_vec[seg_b*DD + j];
      wgv[nt] = rW1[1024*DD + j];    // wg = res_W1 row 1024
      b1v[nt] = rb1[j];
      w2v[nt] = rW2[j];
    }
    #pragma unroll
    for (int mt = 0; mt < 2; ++mt){
      #pragma unroll
      for (int r = 0; r < 4; ++r){
        int row = mt*16 + rgp*4 + r;
        int q = seg_lo + row; if (q > seg_cnt-1) q = seg_cnt-1;
        int gr = alist[q];
        float gt = grc - rate_seq[gr] + cs;    // active rows: commit==1
        float s = 0.f;
        #pragma unroll
        for (int nt = 0; nt < 4; ++nt){
          float y = acc[mt][nt][r] + svv[nt] + gt*wgv[nt] + b1v[nt];
          s += gelu_f(y) * w2v[nt];
        }
        s += __shfl_xor(s, 1, 64);
        s += __shfl_xor(s, 2, 64);
        s += __shfl_xor(s, 4, 64);
        s += __shfl_xor(s, 8, 64);
        if (li == 0) part[wid][row] = s;
      }
    }
    __syncthreads();
    if (tid < 32){
      int q = seg_lo + tid;
      if (q < seg_cnt){
        int gr = alist[q];
        float s = 0.f;
        #pragma unroll
        for (int w = 0; w < 8; ++w) s += part[w][tid];
        float resid = 0.35f * tanhf(s + rb2[0]) * rgate_a[gr];
        float g = grc - rate_seq[gr] + cs;
        // active rows: speech==1, sil_commit==0
        out[gr] = fminf(fmaxf(g + resid, -1.2f), 1.2f);
      }
    }
    __syncthreads();   // protect Af/part before a possible next tile
  }
}

extern "C" void kernel_launch(void* const* d_in, const int* in_sizes, int n_in,
                              void* d_out, int out_size, void* d_ws, size_t ws_size,
                              hipStream_t stream)
{
  const int*   content = (const int*)  d_in[0];
  const float* la      = (const float*)d_in[1];
  const int*   um      = (const int*)  d_in[2];
  const int*   smk     = (const int*)  d_in[3];
  const int*   zm      = (const int*)  d_in[4];
  const float* sep     = (const float*)d_in[5];
  const float* edge    = (const float*)d_in[6];
  const float* stab    = (const float*)d_in[7];
  const float* grate   = (const float*)d_in[8];
  const float* lre     = (const float*)d_in[9];
  const float* spk_e   = (const float*)d_in[10];
  const float* emb     = (const float*)d_in[11];
  const float* fW      = (const float*)d_in[12];
  const float* fb      = (const float*)d_in[13];
  const float* spk_W   = (const float*)d_in[14];
  const float* spk_b   = (const float*)d_in[15];
  const float* cW1     = (const float*)d_in[16];
  const float* cb1     = (const float*)d_in[17];
  const float* cW2     = (const float*)d_in[18];
  const float* cb2     = (const float*)d_in[19];
  const float* rW1     = (const float*)d_in[20];
  const float* rb1     = (const float*)d_in[21];
  const float* rW2     = (const float*)d_in[22];
  const float* rb2     = (const float*)d_in[23];

  char* w = (char*)d_ws;
  unsigned short* wsWqT = (unsigned short*)(w);                 // 524288 B
  size_t off = 524288;
  float* rate_seq = (float*)(w + off); off += MM*4;
  float* rgate_a  = (float*)(w + off); off += MM*4;
  int*   active_list = (int*)(w + off); off += MM*4;
  float* s_vec    = (float*)(w + off); off += BB*DD*4;
  float* spk_ctx  = (float*)(w + off); off += BB*DD*4;
  float* coarse_part = (float*)(w + off); off += 64*4;
  int*   acount   = (int*)(w + off); off += 256;

  pre_kernel<<<136, 512, 0, stream>>>(spk_e, spk_W, spk_b, rW1,
      la, um, smk, zm, stab, lre,
      spk_ctx, wsWqT, rate_seq, rgate_a, active_list, acount);
  prep2_kernel<<<64, 512, 0, stream>>>(spk_ctx, rW1, cW1, cb1, cW2, grate,
                                       s_vec, coarse_part);
  main_kernel<<<256, 512, 0, stream>>>(content, la, sep, edge, emb, fW, fb,
      rate_seq, wsWqT, s_vec, rW1, rb1, rW2, rb2, grate, coarse_part, cb2,
      um, smk, zm, rgate_a, active_list, acount, (float*)d_out);
}

// Round 15
// 41.577 us; speedup vs baseline: 2.6131x; 1.2216x over previous
//
#include <hip/hip_runtime.h>
#include <hip/hip_bf16.h>

// ---- problem constants ----
#define BB 8
#define TT 4096
#define DD 512
#define MM (BB*TT)          // 32768 rows
#define DECAYF 0.95f
#define OMDECAYF (1.0f - 0.95f)

typedef __attribute__((ext_vector_type(8))) short bf16x8;
typedef __attribute__((ext_vector_type(4))) float f32x4;

__device__ __forceinline__ float gelu_f(float x){
  return 0.5f * x * (1.0f + erff(x * 0.70710678118654752f));
}

__device__ __forceinline__ unsigned f2bf(float x){
  unsigned u = __float_as_uint(x);
  return (u + 0x7FFFu + ((u >> 16) & 1u)) >> 16;
}

// ====== K1: blocks 0-63 prep1 (k-sliced) | 64-127 transpose | 128-135 scan ====
__global__ __launch_bounds__(512) void pre_kernel(
    const float* __restrict__ spk_embed, const float* __restrict__ spk_W,
    const float* __restrict__ spk_b, const float* __restrict__ rW1,
    const float* __restrict__ la_g, const int* __restrict__ um,
    const int* __restrict__ sm, const int* __restrict__ zm,
    const float* __restrict__ stab_g, const float* __restrict__ lre,
    float* __restrict__ spk_ctx, unsigned short* __restrict__ wqt,
    float* __restrict__ rate_seq, float* __restrict__ rgate_a,
    int* __restrict__ active_list, int* __restrict__ acount)
{
  __shared__ float se[DD];
  __shared__ float red[8][64];
  __shared__ float tile[64][65];
  __shared__ float wAg[8], wBg[8], wSg[8];
  __shared__ int wcnt[8];
  int blk = blockIdx.x, t = threadIdx.x;
  int lane = t & 63, wid = t >> 6;

  if (blk < 64){
    // ---- prep1: spk_ctx = tanh(spk_embed @ spk_W + spk_b), k-sliced ----
    int b = blk >> 3, d0 = (blk & 7) * 64;
    int dl = lane, ks = wid;
    se[t] = spk_embed[b*DD + t];
    __syncthreads();
    float a = 0.f;
    const float* wp = spk_W + (long)(ks*64)*DD + d0 + dl;
    #pragma unroll 8
    for (int k = 0; k < 64; ++k) a += se[ks*64 + k] * wp[(long)k*DD];
    red[ks][dl] = a;
    __syncthreads();
    if (t < 64){
      float s = spk_b[d0 + t];
      #pragma unroll
      for (int i = 0; i < 8; ++i) s += red[i][t];
      spk_ctx[b*DD + d0 + t] = tanhf(s);
    }
    return;
  }
  if (blk < 128){
    // ---- transpose Wq (k-major f32) -> WqT (n-major bf16) ----
    int tb = blk - 64;
    int nb = (tb & 7) * 64, kb = (tb >> 3) * 64;
    int tx = t & 63, ty = t >> 6;
    #pragma unroll
    for (int i = 0; i < 8; ++i){
      int k = ty + i*8;
      tile[k][tx] = rW1[(long)(kb + k)*DD + nb + tx];
    }
    __syncthreads();
    #pragma unroll
    for (int i = 0; i < 8; ++i){
      int nl = ty + i*8;
      wqt[(long)(nb + nl)*DD + kb + tx] = (unsigned short)f2bf(tile[tx][nl]);
    }
    return;
  }

  // ---- scan: rate_seq + rgate + segmented compaction (batch b) ----
  int b = blk - 128;
  int base = b*TT + t*8;
  float4 la0 = *(const float4*)(la_g + base);
  float4 la1 = *(const float4*)(la_g + base + 4);
  int4 u0 = *(const int4*)(um + base), u1 = *(const int4*)(um + base + 4);
  int4 s0 = *(const int4*)(sm + base), s1 = *(const int4*)(sm + base + 4);
  int4 z0 = *(const int4*)(zm + base), z1 = *(const int4*)(zm + base + 4);
  float4 st0 = *(const float4*)(stab_g + base), st1 = *(const float4*)(stab_g + base + 4);
  float lav[8] = {la0.x,la0.y,la0.z,la0.w,la1.x,la1.y,la1.z,la1.w};
  int uv[8] = {u0.x,u0.y,u0.z,u0.w,u1.x,u1.y,u1.z,u1.w};
  int sv[8] = {s0.x,s0.y,s0.z,s0.w,s1.x,s1.y,s1.z,s1.w};
  int zv[8] = {z0.x,z0.y,z0.z,z0.w,z1.x,z1.y,z1.z,z1.w};
  float stv_[8] = {st0.x,st0.y,st0.z,st0.w,st1.x,st1.y,st1.z,st1.w};
  float spv[8], stv[8];

  float A = 1.f, Bv = 0.f, S = 0.f;
  #pragma unroll
  for (int i = 0; i < 8; ++i){
    float m = uv[i] > 0 ? 1.f : 0.f;
    float sealed = sv[i] > 0 ? 1.f : 0.f;
    float sil = (zv[i] > 0 ? 1.f : 0.f) * m;
    float speech = (m * sealed) * (1.f - sil);
    spv[i] = speech;
    stv[i] = fminf(fmaxf(stv_[i], 0.f), 1.f) * m;
    if (speech > 0.f){
      Bv = DECAYF*Bv + OMDECAYF*lav[i];
      A *= DECAYF;
      S += 1.f;
    }
  }
  #pragma unroll
  for (int d = 1; d < 64; d <<= 1){
    float Au = __shfl_up(A, d, 64);
    float Bu = __shfl_up(Bv, d, 64);
    float Su = __shfl_up(S, d, 64);
    if (lane >= d){ Bv = A*Bu + Bv; A = A*Au; S += Su; }
  }
  if (lane == 63){ wAg[wid] = A; wBg[wid] = Bv; wSg[wid] = S; }
  float Ale = __shfl_up(A, 1, 64), Ble = __shfl_up(Bv, 1, 64), Sle = __shfl_up(S, 1, 64);
  if (lane == 0){ Ale = 1.f; Ble = 0.f; Sle = 0.f; }
  __syncthreads();
  float Awp = 1.f, Bwp = 0.f, Swp = 0.f;
  for (int w = 0; w < wid; ++w){
    Bwp = wAg[w]*Bwp + wBg[w];
    Awp = wAg[w]*Awp;
    Swp += wSg[w];
  }
  float Bex = Ale*Bwp + Ble;
  float Aex = Ale*Awp;
  float Sex = Swp + Sle;

  float rate = Aex*lre[b] + Bex;
  float ps = Sex;
  float ro[8], rg[8];
  #pragma unroll
  for (int i = 0; i < 8; ++i){
    ro[i] = rate;
    float cold = fminf(ps * 0.5f, 1.f);                        // COLD_RUNS=2
    float shortg = fminf(fmaxf(expf(lav[i]) - 1.f, 0.f), 1.f); // MIN_DUR=2
    rg[i] = cold * shortg * stv[i] * spv[i];
    if (spv[i] > 0.f){
      rate = DECAYF*rate + OMDECAYF*lav[i];
      ps += 1.f;
    }
  }
  *(float4*)(rate_seq + base)     = make_float4(ro[0],ro[1],ro[2],ro[3]);
  *(float4*)(rate_seq + base + 4) = make_float4(ro[4],ro[5],ro[6],ro[7]);
  *(float4*)(rgate_a + base)      = make_float4(rg[0],rg[1],rg[2],rg[3]);
  *(float4*)(rgate_a + base + 4)  = make_float4(rg[4],rg[5],rg[6],rg[7]);

  int nact = 0;
  #pragma unroll
  for (int i = 0; i < 8; ++i) nact += (rg[i] != 0.f) ? 1 : 0;
  int inc = nact;
  #pragma unroll
  for (int d = 1; d < 64; d <<= 1){
    int u = __shfl_up(inc, d, 64);
    if (lane >= d) inc += u;
  }
  int myex = inc - nact;
  if (lane == 63) wcnt[wid] = inc;
  __syncthreads();
  int wbase = 0;
  for (int w = 0; w < wid; ++w) wbase += wcnt[w];
  int pos = wbase + myex;
  int* alist = active_list + b*TT;
  #pragma unroll
  for (int i = 0; i < 8; ++i){
    if (rg[i] != 0.f) alist[pos++] = base + i;
  }
  if (t == 0){
    int total = 0;
    #pragma unroll
    for (int w = 0; w < 8; ++w) total += wcnt[w];
    acount[b] = total;
  }
}

// ====== K2: s_vec = spk_ctx@Ws ; coarse hidden partial dot (k-sliced) =========
__global__ __launch_bounds__(512) void prep2_kernel(
    const float* __restrict__ spk_ctx, const float* __restrict__ rW1,
    const float* __restrict__ cW1, const float* __restrict__ cb1,
    const float* __restrict__ cW2, const float* __restrict__ grate,
    float* __restrict__ s_vec, float* __restrict__ coarse_part)
{
  __shared__ float sc[DD];
  __shared__ float red1[8][64];
  __shared__ float red2[8][64];
  int blk = blockIdx.x;
  int b = blk >> 3, d0 = (blk & 7) * 64;
  int t = threadIdx.x, dl = t & 63, ks = t >> 6;
  sc[t] = spk_ctx[b*DD + t];
  __syncthreads();
  float a1 = 0.f, a2 = 0.f;
  const float* wsp = rW1 + (long)(DD + ks*64)*DD + d0 + dl;   // Ws = res_W1[D:2D]
  const float* wcp = cW1 + (long)(ks*64)*DD + d0 + dl;
  #pragma unroll 4
  for (int k = 0; k < 64; ++k){
    float s = sc[ks*64 + k];
    a1 += s * wsp[(long)k*DD];
    a2 += s * wcp[(long)k*DD];
  }
  red1[ks][dl] = a1; red2[ks][dl] = a2;
  __syncthreads();
  if (t < 64){
    int d = d0 + t;
    float s1 = 0.f;
    float s2 = cb1[d] + grate[b] * cW1[(long)DD*DD + d];   // row 512 = grc coeff
    #pragma unroll
    for (int i = 0; i < 8; ++i){ s1 += red1[i][t]; s2 += red2[i][t]; }
    s_vec[b*DD + d] = s1;
    float hv = gelu_f(s2) * cW2[d];
    #pragma unroll
    for (int sh = 1; sh < 64; sh <<= 1) hv += __shfl_xor(hv, sh, 64);
    if (t == 0) coarse_part[blk] = hv;
  }
}

// ====== K3: persistent 256 blocks: baseline slice, then BM=32 gemm tiles =====
// BM=32, BN=512, BK=32, 8 waves; 2-buffer per-wave B staging, barrier-free
// K-loop (counted vmcnt(4)). A-build uses NO union: pack 2 bf16 -> uint and
// store int4 immediately (R14's 32-short union buffer was demoted to scratch:
// VGPR 128 + 21 MB scratch writes = the whole 41 us).
__global__ __launch_bounds__(512) void main_kernel(
    const int* __restrict__ content, const float* __restrict__ la_g,
    const float* __restrict__ sep, const float* __restrict__ edge,
    const float* __restrict__ emb, const float* __restrict__ fW,
    const float* __restrict__ fb, const float* __restrict__ rate_seq,
    const unsigned short* __restrict__ wqt,
    const float* __restrict__ s_vec, const float* __restrict__ rW1,
    const float* __restrict__ rb1, const float* __restrict__ rW2,
    const float* __restrict__ rb2, const float* __restrict__ grate,
    const float* __restrict__ coarse_part, const float* __restrict__ cb2,
    const int* __restrict__ um, const int* __restrict__ sm,
    const int* __restrict__ zm,
    const float* __restrict__ rgate_a, const int* __restrict__ active_list,
    const int* __restrict__ acount, float* __restrict__ out)
{
  __shared__ unsigned short Af[16*32*32];    // [kc][row 32][32k] = 32 KB
  __shared__ unsigned short Bs[2][512*32];   // 64 KB
  __shared__ float part[8][32];
  __shared__ int seg_sh[3];
  int blk = blockIdx.x, tid = threadIdx.x, wid = tid >> 6, lane = tid & 63;

  // ---- baseline slice: 128 rows per block, write rows with rgate==0 ----
  if (tid < 128){
    int gr = blk*128 + tid;
    float rgv = rgate_a[gr];
    if (rgv == 0.f){
      int b = gr >> 12;
      float csum = cb2[0];
      #pragma unroll
      for (int c = 0; c < 8; ++c) csum += coarse_part[b*8 + c];
      float cs = 0.2f * tanhf(csum);
      float m = um[gr] > 0 ? 1.f : 0.f;
      float sealed = sm[gr] > 0 ? 1.f : 0.f;
      float sil = (zm[gr] > 0 ? 1.f : 0.f) * m;
      float commit = m * sealed;
      float speech = commit * (1.f - sil);
      float silc = commit * sil;
      float g = (grate[b] - rate_seq[gr] + cs) * commit;
      out[gr] = fminf(fmaxf(g, -1.2f), 1.2f) * speech
              + fminf(fmaxf(g, -0.35f), 0.35f) * silc;
    }
  }

  const char* wbase = (const char*)wqt;
  auto stageB = [&](unsigned short* dstbuf, int kc){
    int k0b = kc * 64;  // byte offset into each 1024B (512-elem bf16) row
    #pragma unroll
    for (int i = 0; i < 4; ++i){
      int j = wid*4 + i;                      // wave wid owns B-rows 64wid..64wid+63
      int n = j*16 + (lane >> 2);
      int slot = (lane & 3) ^ ((n >> 1) & 3);
      const char* src = wbase + (long)n*1024 + k0b + slot*16;
      char* dst = (char*)dstbuf + j*1024 + (lane << 4);
      __builtin_amdgcn_global_load_lds(
          (const __attribute__((address_space(1))) void*)src,
          (__attribute__((address_space(3))) void*)dst, 16, 0, 0);
    }
  };

  // ---- gemm tiles (BM=32): p = blk, blk+256, ... ----
  for (int p = blk; ; p += 256){
    if (tid == 0){
      int cum = 0, sb = -1, slo = 0, scnt = 0;
      #pragma unroll
      for (int b = 0; b < BB; ++b){
        int c = acount[b];
        int nb = (c + 31) >> 5;
        if (sb < 0 && p < cum + nb){ sb = b; slo = (p - cum) * 32; scnt = c; }
        cum += nb;
      }
      seg_sh[0] = sb; seg_sh[1] = slo; seg_sh[2] = scnt;
    }
    __syncthreads();
    int seg_b = seg_sh[0], seg_lo = seg_sh[1], seg_cnt = seg_sh[2];
    if (seg_b < 0) break;
    const int* alist = active_list + seg_b*TT;

    float csum = cb2[0];
    #pragma unroll
    for (int c = 0; c < 8; ++c) csum += coarse_part[seg_b*8 + c];
    float cs = 0.2f * tanhf(csum);
    float grc = grate[seg_b];

    stageB(&Bs[0][0], 0);   // latency hides under A-build

    // ---- build A tile: 512 (row,chunk) pairs, 1 per thread; NO union ----
    {
      int rr = tid >> 4, kc = tid & 15;
      int q = seg_lo + rr; if (q > seg_cnt-1) q = seg_cnt-1;
      int gr = alist[q];
      float la = la_g[gr], rate = rate_seq[gr];
      float sepv = sep[gr], edgev = edge[gr];
      int k0 = kc * 32;
      const float* er = emb + (long)content[gr]*DD + k0;
      int c = (rr >> 1) & 3;
      char* abase = (char*)Af + kc*2048 + rr*64;
      #pragma unroll
      for (int s2 = 0; s2 < 4; ++s2){
        int kk = k0 + s2*8;
        float4 e0 = *(const float4*)(er + s2*8);
        float4 e1 = *(const float4*)(er + s2*8 + 4);
        float4 w00 = *(const float4*)(fW + kk);
        float4 w01 = *(const float4*)(fW + kk + 4);
        float4 w10 = *(const float4*)(fW + DD + kk);
        float4 w11 = *(const float4*)(fW + DD + kk + 4);
        float4 w30 = *(const float4*)(fW + 3*DD + kk);
        float4 w31 = *(const float4*)(fW + 3*DD + kk + 4);
        float4 w40 = *(const float4*)(fW + 4*DD + kk);
        float4 w41 = *(const float4*)(fW + 4*DD + kk + 4);
        float4 b0 = *(const float4*)(fb + kk);
        float4 b1 = *(const float4*)(fb + kk + 4);
        unsigned v0 = f2bf(gelu_f(e0.x + la*w00.x + rate*w10.x + sepv*w30.x + edgev*w40.x + b0.x));
        unsigned v1 = f2bf(gelu_f(e0.y + la*w00.y + rate*w10.y + sepv*w30.y + edgev*w40.y + b0.y));
        unsigned v2 = f2bf(gelu_f(e0.z + la*w00.z + rate*w10.z + sepv*w30.z + edgev*w40.z + b0.z));
        unsigned v3 = f2bf(gelu_f(e0.w + la*w00.w + rate*w10.w + sepv*w30.w + edgev*w40.w + b0.w));
        unsigned v4 = f2bf(gelu_f(e1.x + la*w01.x + rate*w11.x + sepv*w31.x + edgev*w41.x + b1.x));
        unsigned v5 = f2bf(gelu_f(e1.y + la*w01.y + rate*w11.y + sepv*w31.y + edgev*w41.y + b1.y));
        unsigned v6 = f2bf(gelu_f(e1.z + la*w01.z + rate*w11.z + sepv*w31.z + edgev*w41.z + b1.z));
        unsigned v7 = f2bf(gelu_f(e1.w + la*w01.w + rate*w11.w + sepv*w31.w + edgev*w41.w + b1.w));
        int4 pkv = make_int4((int)((v1 << 16) | v0), (int)((v3 << 16) | v2),
                             (int)((v5 << 16) | v4), (int)((v7 << 16) | v6));
        *(int4*)(abase + ((s2 ^ c) << 4)) = pkv;
      }
    }
    __syncthreads();   // Af visible to all waves (also drains stage(0))

    f32x4 acc[2][4];
    #pragma unroll
    for (int i = 0; i < 2; ++i)
      #pragma unroll
      for (int j = 0; j < 4; ++j) acc[i][j] = (f32x4){0.f,0.f,0.f,0.f};

    int rgp = lane >> 4, li = lane & 15;
    #pragma unroll
    for (int kc = 0; kc < 16; ++kc){
      // issue next chunk into the other buffer (per-wave-disjoint B rows)
      if (kc < 15) stageB(&Bs[(kc+1)&1][0], kc+1);
      // per-wave wait: kc's 4 loads done (kc+1's may stay in flight)
      if (kc < 15) asm volatile("s_waitcnt vmcnt(4)" ::: "memory");
      else         asm volatile("s_waitcnt vmcnt(0)" ::: "memory");
      const char* bsb = (const char*)&Bs[kc&1][0];
      bf16x8 a[2], bb[4];
      #pragma unroll
      for (int mt = 0; mt < 2; ++mt){
        int row = mt*16 + li;
        int slot = rgp ^ ((row >> 1) & 3);
        a[mt] = *(const bf16x8*)((const char*)Af + kc*2048 + row*64 + (slot << 4));
      }
      #pragma unroll
      for (int nt = 0; nt < 4; ++nt){
        int n = wid*64 + nt*16 + li;
        int slot = rgp ^ ((n >> 1) & 3);
        bb[nt] = *(const bf16x8*)(bsb + n*64 + slot*16);
      }
      #pragma unroll
      for (int mt = 0; mt < 2; ++mt)
        #pragma unroll
        for (int nt = 0; nt < 4; ++nt)
          acc[mt][nt] = __builtin_amdgcn_mfma_f32_16x16x32_bf16(a[mt], bb[nt], acc[mt][nt], 0, 0, 0);
    }

    // epilogue: h = gelu(y + s_vec[b] + gterm*wg + b1); dot with res_W2
    float svv[4], wgv[4], b1v[4], w2v[4];
    #pragma unroll
    for (int nt = 0; nt < 4; ++nt){
      int j = wid*64 + nt*16 + li;
      svv[nt] = s_vec[seg_b*DD + j];
      wgv[nt] = rW1[1024*DD + j];    // wg = res_W1 row 1024
      b1v[nt] = rb1[j];
      w2v[nt] = rW2[j];
    }
    #pragma unroll
    for (int mt = 0; mt < 2; ++mt){
      #pragma unroll
      for (int r = 0; r < 4; ++r){
        int row = mt*16 + rgp*4 + r;
        int q = seg_lo + row; if (q > seg_cnt-1) q = seg_cnt-1;
        int gr = alist[q];
        float gt = grc - rate_seq[gr] + cs;    // active rows: commit==1
        float s = 0.f;
        #pragma unroll
        for (int nt = 0; nt < 4; ++nt){
          float y = acc[mt][nt][r] + svv[nt] + gt*wgv[nt] + b1v[nt];
          s += gelu_f(y) * w2v[nt];
        }
        s += __shfl_xor(s, 1, 64);
        s += __shfl_xor(s, 2, 64);
        s += __shfl_xor(s, 4, 64);
        s += __shfl_xor(s, 8, 64);
        if (li == 0) part[wid][row] = s;
      }
    }
    __syncthreads();
    if (tid < 32){
      int q = seg_lo + tid;
      if (q < seg_cnt){
        int gr = alist[q];
        float s = 0.f;
        #pragma unroll
        for (int w = 0; w < 8; ++w) s += part[w][tid];
        float resid = 0.35f * tanhf(s + rb2[0]) * rgate_a[gr];
        float g = grc - rate_seq[gr] + cs;
        // active rows: speech==1, sil_commit==0
        out[gr] = fminf(fmaxf(g + resid, -1.2f), 1.2f);
      }
    }
    __syncthreads();   // protect Af/part before a possible next tile
  }
}

extern "C" void kernel_launch(void* const* d_in, const int* in_sizes, int n_in,
                              void* d_out, int out_size, void* d_ws, size_t ws_size,
                              hipStream_t stream)
{
  const int*   content = (const int*)  d_in[0];
  const float* la      = (const float*)d_in[1];
  const int*   um      = (const int*)  d_in[2];
  const int*   smk     = (const int*)  d_in[3];
  const int*   zm      = (const int*)  d_in[4];
  const float* sep     = (const float*)d_in[5];
  const float* edge    = (const float*)d_in[6];
  const float* stab    = (const float*)d_in[7];
  const float* grate   = (const float*)d_in[8];
  const float* lre     = (const float*)d_in[9];
  const float* spk_e   = (const float*)d_in[10];
  const float* emb     = (const float*)d_in[11];
  const float* fW      = (const float*)d_in[12];
  const float* fb      = (const float*)d_in[13];
  const float* spk_W   = (const float*)d_in[14];
  const float* spk_b   = (const float*)d_in[15];
  const float* cW1     = (const float*)d_in[16];
  const float* cb1     = (const float*)d_in[17];
  const float* cW2     = (const float*)d_in[18];
  const float* cb2     = (const float*)d_in[19];
  const float* rW1     = (const float*)d_in[20];
  const float* rb1     = (const float*)d_in[21];
  const float* rW2     = (const float*)d_in[22];
  const float* rb2     = (const float*)d_in[23];

  char* w = (char*)d_ws;
  unsigned short* wsWqT = (unsigned short*)(w);                 // 524288 B
  size_t off = 524288;
  float* rate_seq = (float*)(w + off); off += MM*4;
  float* rgate_a  = (float*)(w + off); off += MM*4;
  int*   active_list = (int*)(w + off); off += MM*4;
  float* s_vec    = (float*)(w + off); off += BB*DD*4;
  float* spk_ctx  = (float*)(w + off); off += BB*DD*4;
  float* coarse_part = (float*)(w + off); off += 64*4;
  int*   acount   = (int*)(w + off); off += 256;

  pre_kernel<<<136, 512, 0, stream>>>(spk_e, spk_W, spk_b, rW1,
      la, um, smk, zm, stab, lre,
      spk_ctx, wsWqT, rate_seq, rgate_a, active_list, acount);
  prep2_kernel<<<64, 512, 0, stream>>>(spk_ctx, rW1, cW1, cb1, cW2, grate,
                                       s_vec, coarse_part);
  main_kernel<<<256, 512, 0, stream>>>(content, la, sep, edge, emb, fW, fb,
      rate_seq, wsWqT, s_vec, rW1, rb1, rW2, rb2, grate, coarse_part, cb2,
      um, smk, zm, rgate_a, active_list, acount, (float*)d_out);
}

// Round 16
// 35.274 us; speedup vs baseline: 3.0801x; 1.1787x over previous
//
#include <hip/hip_runtime.h>
#include <hip/hip_bf16.h>

// ---- problem constants ----
#define BB 8
#define TT 4096
#define DD 512
#define MM (BB*TT)          // 32768 rows
#define DECAYF 0.95f
#define OMDECAYF (1.0f - 0.95f)

typedef __attribute__((ext_vector_type(8))) short bf16x8;
typedef __attribute__((ext_vector_type(4))) float f32x4;

__device__ __forceinline__ float gelu_f(float x){
  return 0.5f * x * (1.0f + erff(x * 0.70710678118654752f));
}

__device__ __forceinline__ unsigned f2bf(float x){
  unsigned u = __float_as_uint(x);
  return (u + 0x7FFFu + ((u >> 16) & 1u)) >> 16;
}

// ====== K1: blocks 0-63 prep1 (k-sliced) | 64-127 transpose | 128-135 scan ====
__global__ __launch_bounds__(512) void pre_kernel(
    const float* __restrict__ spk_embed, const float* __restrict__ spk_W,
    const float* __restrict__ spk_b, const float* __restrict__ rW1,
    const float* __restrict__ la_g, const int* __restrict__ um,
    const int* __restrict__ sm, const int* __restrict__ zm,
    const float* __restrict__ stab_g, const float* __restrict__ lre,
    float* __restrict__ spk_ctx, unsigned short* __restrict__ wqt,
    float* __restrict__ rate_seq, float* __restrict__ rgate_a,
    int* __restrict__ active_list, int* __restrict__ acount)
{
  __shared__ float se[DD];
  __shared__ float red[8][64];
  __shared__ float tile[64][65];
  __shared__ float wAg[8], wBg[8], wSg[8];
  __shared__ int wcnt[8];
  int blk = blockIdx.x, t = threadIdx.x;
  int lane = t & 63, wid = t >> 6;

  if (blk < 64){
    // ---- prep1: spk_ctx = tanh(spk_embed @ spk_W + spk_b), k-sliced ----
    int b = blk >> 3, d0 = (blk & 7) * 64;
    int dl = lane, ks = wid;
    se[t] = spk_embed[b*DD + t];
    __syncthreads();
    float a = 0.f;
    const float* wp = spk_W + (long)(ks*64)*DD + d0 + dl;
    #pragma unroll 8
    for (int k = 0; k < 64; ++k) a += se[ks*64 + k] * wp[(long)k*DD];
    red[ks][dl] = a;
    __syncthreads();
    if (t < 64){
      float s = spk_b[d0 + t];
      #pragma unroll
      for (int i = 0; i < 8; ++i) s += red[i][t];
      spk_ctx[b*DD + d0 + t] = tanhf(s);
    }
    return;
  }
  if (blk < 128){
    // ---- transpose Wq (k-major f32) -> WqT (n-major bf16) ----
    int tb = blk - 64;
    int nb = (tb & 7) * 64, kb = (tb >> 3) * 64;
    int tx = t & 63, ty = t >> 6;
    #pragma unroll
    for (int i = 0; i < 8; ++i){
      int k = ty + i*8;
      tile[k][tx] = rW1[(long)(kb + k)*DD + nb + tx];
    }
    __syncthreads();
    #pragma unroll
    for (int i = 0; i < 8; ++i){
      int nl = ty + i*8;
      wqt[(long)(nb + nl)*DD + kb + tx] = (unsigned short)f2bf(tile[tx][nl]);
    }
    return;
  }

  // ---- scan: rate_seq + rgate + segmented compaction (batch b) ----
  int b = blk - 128;
  int base = b*TT + t*8;
  float4 la0 = *(const float4*)(la_g + base);
  float4 la1 = *(const float4*)(la_g + base + 4);
  int4 u0 = *(const int4*)(um + base), u1 = *(const int4*)(um + base + 4);
  int4 s0 = *(const int4*)(sm + base), s1 = *(const int4*)(sm + base + 4);
  int4 z0 = *(const int4*)(zm + base), z1 = *(const int4*)(zm + base + 4);
  float4 st0 = *(const float4*)(stab_g + base), st1 = *(const float4*)(stab_g + base + 4);
  float lav[8] = {la0.x,la0.y,la0.z,la0.w,la1.x,la1.y,la1.z,la1.w};
  int uv[8] = {u0.x,u0.y,u0.z,u0.w,u1.x,u1.y,u1.z,u1.w};
  int sv[8] = {s0.x,s0.y,s0.z,s0.w,s1.x,s1.y,s1.z,s1.w};
  int zv[8] = {z0.x,z0.y,z0.z,z0.w,z1.x,z1.y,z1.z,z1.w};
  float stv_[8] = {st0.x,st0.y,st0.z,st0.w,st1.x,st1.y,st1.z,st1.w};
  float spv[8], stv[8];

  float A = 1.f, Bv = 0.f, S = 0.f;
  #pragma unroll
  for (int i = 0; i < 8; ++i){
    float m = uv[i] > 0 ? 1.f : 0.f;
    float sealed = sv[i] > 0 ? 1.f : 0.f;
    float sil = (zv[i] > 0 ? 1.f : 0.f) * m;
    float speech = (m * sealed) * (1.f - sil);
    spv[i] = speech;
    stv[i] = fminf(fmaxf(stv_[i], 0.f), 1.f) * m;
    if (speech > 0.f){
      Bv = DECAYF*Bv + OMDECAYF*lav[i];
      A *= DECAYF;
      S += 1.f;
    }
  }
  #pragma unroll
  for (int d = 1; d < 64; d <<= 1){
    float Au = __shfl_up(A, d, 64);
    float Bu = __shfl_up(Bv, d, 64);
    float Su = __shfl_up(S, d, 64);
    if (lane >= d){ Bv = A*Bu + Bv; A = A*Au; S += Su; }
  }
  if (lane == 63){ wAg[wid] = A; wBg[wid] = Bv; wSg[wid] = S; }
  float Ale = __shfl_up(A, 1, 64), Ble = __shfl_up(Bv, 1, 64), Sle = __shfl_up(S, 1, 64);
  if (lane == 0){ Ale = 1.f; Ble = 0.f; Sle = 0.f; }
  __syncthreads();
  float Awp = 1.f, Bwp = 0.f, Swp = 0.f;
  for (int w = 0; w < wid; ++w){
    Bwp = wAg[w]*Bwp + wBg[w];
    Awp = wAg[w]*Awp;
    Swp += wSg[w];
  }
  float Bex = Ale*Bwp + Ble;
  float Aex = Ale*Awp;
  float Sex = Swp + Sle;

  float rate = Aex*lre[b] + Bex;
  float ps = Sex;
  float ro[8], rg[8];
  #pragma unroll
  for (int i = 0; i < 8; ++i){
    ro[i] = rate;
    float cold = fminf(ps * 0.5f, 1.f);                        // COLD_RUNS=2
    float shortg = fminf(fmaxf(expf(lav[i]) - 1.f, 0.f), 1.f); // MIN_DUR=2
    rg[i] = cold * shortg * stv[i] * spv[i];
    if (spv[i] > 0.f){
      rate = DECAYF*rate + OMDECAYF*lav[i];
      ps += 1.f;
    }
  }
  *(float4*)(rate_seq + base)     = make_float4(ro[0],ro[1],ro[2],ro[3]);
  *(float4*)(rate_seq + base + 4) = make_float4(ro[4],ro[5],ro[6],ro[7]);
  *(float4*)(rgate_a + base)      = make_float4(rg[0],rg[1],rg[2],rg[3]);
  *(float4*)(rgate_a + base + 4)  = make_float4(rg[4],rg[5],rg[6],rg[7]);

  int nact = 0;
  #pragma unroll
  for (int i = 0; i < 8; ++i) nact += (rg[i] != 0.f) ? 1 : 0;
  int inc = nact;
  #pragma unroll
  for (int d = 1; d < 64; d <<= 1){
    int u = __shfl_up(inc, d, 64);
    if (lane >= d) inc += u;
  }
  int myex = inc - nact;
  if (lane == 63) wcnt[wid] = inc;
  __syncthreads();
  int wbase = 0;
  for (int w = 0; w < wid; ++w) wbase += wcnt[w];
  int pos = wbase + myex;
  int* alist = active_list + b*TT;
  #pragma unroll
  for (int i = 0; i < 8; ++i){
    if (rg[i] != 0.f) alist[pos++] = base + i;
  }
  if (t == 0){
    int total = 0;
    #pragma unroll
    for (int w = 0; w < 8; ++w) total += wcnt[w];
    acount[b] = total;
  }
}

// ====== K2: blocks 0-63 prep2 | blocks 64-575 build_q (high occupancy) =======
__global__ __launch_bounds__(512) void mid_kernel(
    const float* __restrict__ spk_ctx, const float* __restrict__ rW1,
    const float* __restrict__ cW1, const float* __restrict__ cb1,
    const float* __restrict__ cW2, const float* __restrict__ grate,
    const int* __restrict__ content, const float* __restrict__ la_g,
    const float* __restrict__ sep, const float* __restrict__ edge,
    const float* __restrict__ emb, const float* __restrict__ fW,
    const float* __restrict__ fb, const float* __restrict__ rate_seq,
    const int* __restrict__ active_list, const int* __restrict__ acount,
    float* __restrict__ s_vec, float* __restrict__ coarse_part,
    unsigned short* __restrict__ wsQ)
{
  int blk = blockIdx.x, t = threadIdx.x;
  int lane = t & 63, wid = t >> 6;

  if (blk < 64){
    // ---- prep2: s_vec + coarse hidden partial (k-sliced, R8-proven) ----
    __shared__ float sc[DD];
    __shared__ float red1[8][64];
    __shared__ float red2[8][64];
    int b = blk >> 3, d0 = (blk & 7) * 64;
    int dl = lane, ks = wid;
    sc[t] = spk_ctx[b*DD + t];
    __syncthreads();
    float a1 = 0.f, a2 = 0.f;
    const float* wsp = rW1 + (long)(DD + ks*64)*DD + d0 + dl;   // Ws = res_W1[D:2D]
    const float* wcp = cW1 + (long)(ks*64)*DD + d0 + dl;
    #pragma unroll 4
    for (int k = 0; k < 64; ++k){
      float s = sc[ks*64 + k];
      a1 += s * wsp[(long)k*DD];
      a2 += s * wcp[(long)k*DD];
    }
    red1[ks][dl] = a1; red2[ks][dl] = a2;
    __syncthreads();
    if (t < 64){
      int d = d0 + t;
      float s1 = 0.f;
      float s2 = cb1[d] + grate[b] * cW1[(long)DD*DD + d];   // row 512 = grc coeff
      #pragma unroll
      for (int i = 0; i < 8; ++i){ s1 += red1[i][t]; s2 += red2[i][t]; }
      s_vec[b*DD + d] = s1;
      float hv = gelu_f(s2) * cW2[d];
      #pragma unroll
      for (int sh = 1; sh < 64; sh <<= 1) hv += __shfl_xor(hv, sh, 64);
      if (t == 0) coarse_part[blk] = hv;
    }
    return;
  }

  // ---- build_q: batch b, 64 blocks x 8 waves = 512 row-slots, stride 512 ----
  int tb = blk - 64;
  int b = tb >> 6;
  int slot0 = (tb & 63) * 8 + wid;
  int cnt = acount[b];
  const int* alist = active_list + b*TT;
  int c0 = lane * 8;
  for (int j = slot0; j < cnt; j += 512){
    int gr = alist[j];
    float la = la_g[gr], rate = rate_seq[gr];
    float sepv = sep[gr], edgev = edge[gr];
    const float* er = emb + (long)content[gr]*DD + c0;
    float4 e0 = *(const float4*)(er), e1 = *(const float4*)(er + 4);
    // active rows: sil=0 -> skip fW row 2
    float4 w00 = *(const float4*)(fW + c0),        w01 = *(const float4*)(fW + c0 + 4);
    float4 w10 = *(const float4*)(fW + DD + c0),   w11 = *(const float4*)(fW + DD + c0 + 4);
    float4 w30 = *(const float4*)(fW + 3*DD + c0), w31 = *(const float4*)(fW + 3*DD + c0 + 4);
    float4 w40 = *(const float4*)(fW + 4*DD + c0), w41 = *(const float4*)(fW + 4*DD + c0 + 4);
    float4 b0 = *(const float4*)(fb + c0), b1 = *(const float4*)(fb + c0 + 4);
    unsigned v0 = f2bf(gelu_f(e0.x + la*w00.x + rate*w10.x + sepv*w30.x + edgev*w40.x + b0.x));
    unsigned v1 = f2bf(gelu_f(e0.y + la*w00.y + rate*w10.y + sepv*w30.y + edgev*w40.y + b0.y));
    unsigned v2 = f2bf(gelu_f(e0.z + la*w00.z + rate*w10.z + sepv*w30.z + edgev*w40.z + b0.z));
    unsigned v3 = f2bf(gelu_f(e0.w + la*w00.w + rate*w10.w + sepv*w30.w + edgev*w40.w + b0.w));
    unsigned v4 = f2bf(gelu_f(e1.x + la*w01.x + rate*w11.x + sepv*w31.x + edgev*w41.x + b1.x));
    unsigned v5 = f2bf(gelu_f(e1.y + la*w01.y + rate*w11.y + sepv*w31.y + edgev*w41.y + b1.y));
    unsigned v6 = f2bf(gelu_f(e1.z + la*w01.z + rate*w11.z + sepv*w31.z + edgev*w41.z + b1.z));
    unsigned v7 = f2bf(gelu_f(e1.w + la*w01.w + rate*w11.w + sepv*w31.w + edgev*w41.w + b1.w));
    int4 pkv = make_int4((int)((v1 << 16) | v0), (int)((v3 << 16) | v2),
                         (int)((v5 << 16) | v4), (int)((v7 << 16) | v6));
    *(int4*)(wsQ + (long)(b*TT + j)*DD + c0) = pkv;
  }
}

// ====== K3: persistent 256 blocks: baseline slice, then BM=32 gemm tiles =====
// A AND B both DMA-staged via global_load_lds; no VALU A-build in this kernel.
// Per-wave B staging barrier-free (counted vmcnt(4)); A fully staged in the
// prologue behind one vmcnt(0)+barrier.
__global__ __launch_bounds__(512) void main_kernel(
    const float* __restrict__ rate_seq, const unsigned short* __restrict__ wsQ,
    const unsigned short* __restrict__ wqt,
    const float* __restrict__ s_vec, const float* __restrict__ rW1,
    const float* __restrict__ rb1, const float* __restrict__ rW2,
    const float* __restrict__ rb2, const float* __restrict__ grate,
    const float* __restrict__ coarse_part, const float* __restrict__ cb2,
    const int* __restrict__ um, const int* __restrict__ sm,
    const int* __restrict__ zm,
    const float* __restrict__ rgate_a, const int* __restrict__ active_list,
    const int* __restrict__ acount, float* __restrict__ out)
{
  __shared__ unsigned short Af[16*32*32];    // [kc][row 32][32k] = 32 KB
  __shared__ unsigned short Bs[2][512*32];   // 64 KB
  __shared__ float part[8][32];
  __shared__ int seg_sh[3];
  int blk = blockIdx.x, tid = threadIdx.x, wid = tid >> 6, lane = tid & 63;

  // ---- baseline slice: 128 rows per block, write rows with rgate==0 ----
  if (tid < 128){
    int gr = blk*128 + tid;
    float rgv = rgate_a[gr];
    if (rgv == 0.f){
      int b = gr >> 12;
      float csum = cb2[0];
      #pragma unroll
      for (int c = 0; c < 8; ++c) csum += coarse_part[b*8 + c];
      float cs = 0.2f * tanhf(csum);
      float m = um[gr] > 0 ? 1.f : 0.f;
      float sealed = sm[gr] > 0 ? 1.f : 0.f;
      float sil = (zm[gr] > 0 ? 1.f : 0.f) * m;
      float commit = m * sealed;
      float speech = commit * (1.f - sil);
      float silc = commit * sil;
      float g = (grate[b] - rate_seq[gr] + cs) * commit;
      out[gr] = fminf(fmaxf(g, -1.2f), 1.2f) * speech
              + fminf(fmaxf(g, -0.35f), 0.35f) * silc;
    }
  }

  const char* wbase = (const char*)wqt;
  auto stageB = [&](unsigned short* dstbuf, int kc){
    int k0b = kc * 64;  // byte offset into each 1024B (512-elem bf16) row
    #pragma unroll
    for (int i = 0; i < 4; ++i){
      int j = wid*4 + i;                      // wave wid owns B-rows 64wid..64wid+63
      int n = j*16 + (lane >> 2);
      int slot = (lane & 3) ^ ((n >> 1) & 3);
      const char* src = wbase + (long)n*1024 + k0b + slot*16;
      char* dst = (char*)dstbuf + j*1024 + (lane << 4);
      __builtin_amdgcn_global_load_lds(
          (const __attribute__((address_space(1))) void*)src,
          (__attribute__((address_space(3))) void*)dst, 16, 0, 0);
    }
  };

  // ---- gemm tiles (BM=32): p = blk, blk+256, ... ----
  for (int p = blk; ; p += 256){
    if (tid == 0){
      int cum = 0, sb = -1, slo = 0, scnt = 0;
      #pragma unroll
      for (int b = 0; b < BB; ++b){
        int c = acount[b];
        int nb = (c + 31) >> 5;
        if (sb < 0 && p < cum + nb){ sb = b; slo = (p - cum) * 32; scnt = c; }
        cum += nb;
      }
      seg_sh[0] = sb; seg_sh[1] = slo; seg_sh[2] = scnt;
    }
    __syncthreads();
    int seg_b = seg_sh[0], seg_lo = seg_sh[1], seg_cnt = seg_sh[2];
    if (seg_b < 0) break;
    const int* alist = active_list + seg_b*TT;
    const char* qseg = (const char*)(wsQ + (long)(seg_b*TT + seg_lo)*DD);

    float csum = cb2[0];
    #pragma unroll
    for (int c = 0; c < 8; ++c) csum += coarse_part[seg_b*8 + c];
    float cs = 0.2f * tanhf(csum);
    float grc = grate[seg_b];

    // ---- prologue: DMA-stage the ENTIRE A tile (32 insts over 8 waves) ----
    #pragma unroll
    for (int i = 0; i < 4; ++i){
      int idx = wid + i*8;                 // 0..31
      int kcA = idx >> 1, half = idx & 1;
      int row = half*16 + (lane >> 2);     // 0..31
      int slot = (lane & 3) ^ ((row >> 1) & 3);
      const char* src = qseg + (long)row*1024 + kcA*64 + slot*16;
      char* dst = (char*)Af + kcA*2048 + half*1024 + (lane << 4);
      __builtin_amdgcn_global_load_lds(
          (const __attribute__((address_space(1))) void*)src,
          (__attribute__((address_space(3))) void*)dst, 16, 0, 0);
    }
    stageB(&Bs[0][0], 0);
    asm volatile("s_waitcnt vmcnt(0)" ::: "memory");
    __syncthreads();   // all waves' A + B0 landed

    f32x4 acc[2][4];
    #pragma unroll
    for (int i = 0; i < 2; ++i)
      #pragma unroll
      for (int j = 0; j < 4; ++j) acc[i][j] = (f32x4){0.f,0.f,0.f,0.f};

    int rgp = lane >> 4, li = lane & 15;
    #pragma unroll
    for (int kc = 0; kc < 16; ++kc){
      // issue next chunk into the other buffer (per-wave-disjoint B rows)
      if (kc < 15) stageB(&Bs[(kc+1)&1][0], kc+1);
      // per-wave wait: kc's 4 loads done (kc+1's may stay in flight)
      if (kc < 15) asm volatile("s_waitcnt vmcnt(4)" ::: "memory");
      else         asm volatile("s_waitcnt vmcnt(0)" ::: "memory");
      const char* bsb = (const char*)&Bs[kc&1][0];
      bf16x8 a[2], bb[4];
      #pragma unroll
      for (int mt = 0; mt < 2; ++mt){
        int row = mt*16 + li;
        int slot = rgp ^ ((row >> 1) & 3);
        a[mt] = *(const bf16x8*)((const char*)Af + kc*2048 + row*64 + (slot << 4));
      }
      #pragma unroll
      for (int nt = 0; nt < 4; ++nt){
        int n = wid*64 + nt*16 + li;
        int slot = rgp ^ ((n >> 1) & 3);
        bb[nt] = *(const bf16x8*)(bsb + n*64 + slot*16);
      }
      #pragma unroll
      for (int mt = 0; mt < 2; ++mt)
        #pragma unroll
        for (int nt = 0; nt < 4; ++nt)
          acc[mt][nt] = __builtin_amdgcn_mfma_f32_16x16x32_bf16(a[mt], bb[nt], acc[mt][nt], 0, 0, 0);
    }

    // epilogue: h = gelu(y + s_vec[b] + gterm*wg + b1); dot with res_W2
    float svv[4], wgv[4], b1v[4], w2v[4];
    #pragma unroll
    for (int nt = 0; nt < 4; ++nt){
      int j = wid*64 + nt*16 + li;
      svv[nt] = s_vec[seg_b*DD + j];
      wgv[nt] = rW1[1024*DD + j];    // wg = res_W1 row 1024
      b1v[nt] = rb1[j];
      w2v[nt] = rW2[j];
    }
    #pragma unroll
    for (int mt = 0; mt < 2; ++mt){
      #pragma unroll
      for (int r = 0; r < 4; ++r){
        int row = mt*16 + rgp*4 + r;
        int q = seg_lo + row; if (q > seg_cnt-1) q = seg_cnt-1;
        int gr = alist[q];
        float gt = grc - rate_seq[gr] + cs;    // active rows: commit==1
        float s = 0.f;
        #pragma unroll
        for (int nt = 0; nt < 4; ++nt){
          float y = acc[mt][nt][r] + svv[nt] + gt*wgv[nt] + b1v[nt];
          s += gelu_f(y) * w2v[nt];
        }
        s += __shfl_xor(s, 1, 64);
        s += __shfl_xor(s, 2, 64);
        s += __shfl_xor(s, 4, 64);
        s += __shfl_xor(s, 8, 64);
        if (li == 0) part[wid][row] = s;
      }
    }
    __syncthreads();
    if (tid < 32){
      int q = seg_lo + tid;
      if (q < seg_cnt){
        int gr = alist[q];
        float s = 0.f;
        #pragma unroll
        for (int w = 0; w < 8; ++w) s += part[w][tid];
        float resid = 0.35f * tanhf(s + rb2[0]) * rgate_a[gr];
        float g = grc - rate_seq[gr] + cs;
        // active rows: speech==1, sil_commit==0
        out[gr] = fminf(fmaxf(g + resid, -1.2f), 1.2f);
      }
    }
    __syncthreads();   // protect Af/part before a possible next tile
  }
}

extern "C" void kernel_launch(void* const* d_in, const int* in_sizes, int n_in,
                              void* d_out, int out_size, void* d_ws, size_t ws_size,
                              hipStream_t stream)
{
  const int*   content = (const int*)  d_in[0];
  const float* la      = (const float*)d_in[1];
  const int*   um      = (const int*)  d_in[2];
  const int*   smk     = (const int*)  d_in[3];
  const int*   zm      = (const int*)  d_in[4];
  const float* sep     = (const float*)d_in[5];
  const float* edge    = (const float*)d_in[6];
  const float* stab    = (const float*)d_in[7];
  const float* grate   = (const float*)d_in[8];
  const float* lre     = (const float*)d_in[9];
  const float* spk_e   = (const float*)d_in[10];
  const float* emb     = (const float*)d_in[11];
  const float* fW      = (const float*)d_in[12];
  const float* fb      = (const float*)d_in[13];
  const float* spk_W   = (const float*)d_in[14];
  const float* spk_b   = (const float*)d_in[15];
  const float* cW1     = (const float*)d_in[16];
  const float* cb1     = (const float*)d_in[17];
  const float* cW2     = (const float*)d_in[18];
  const float* cb2     = (const float*)d_in[19];
  const float* rW1     = (const float*)d_in[20];
  const float* rb1     = (const float*)d_in[21];
  const float* rW2     = (const float*)d_in[22];
  const float* rb2     = (const float*)d_in[23];

  char* w = (char*)d_ws;
  unsigned short* wsQ   = (unsigned short*)(w);                 // 33554432 B
  unsigned short* wsWqT = (unsigned short*)(w + 33554432);      // 524288 B
  size_t off = 33554432 + 524288;
  float* rate_seq = (float*)(w + off); off += MM*4;
  float* rgate_a  = (float*)(w + off); off += MM*4;
  int*   active_list = (int*)(w + off); off += MM*4;
  float* s_vec    = (float*)(w + off); off += BB*DD*4;
  float* spk_ctx  = (float*)(w + off); off += BB*DD*4;
  float* coarse_part = (float*)(w + off); off += 64*4;
  int*   acount   = (int*)(w + off); off += 256;

  pre_kernel<<<136, 512, 0, stream>>>(spk_e, spk_W, spk_b, rW1,
      la, um, smk, zm, stab, lre,
      spk_ctx, wsWqT, rate_seq, rgate_a, active_list, acount);
  mid_kernel<<<576, 512, 0, stream>>>(spk_ctx, rW1, cW1, cb1, cW2, grate,
      content, la, sep, edge, emb, fW, fb, rate_seq, active_list, acount,
      s_vec, coarse_part, wsQ);
  main_kernel<<<256, 512, 0, stream>>>(rate_seq, wsQ, wsWqT,
      s_vec, rW1, rb1, rW2, rb2, grate, coarse_part, cb2,
      um, smk, zm, rgate_a, active_list, acount, (float*)d_out);
}